// Round 7
// baseline (1469.552 us; speedup 1.0000x reference)
//
#include <hip/hip_runtime.h>
#include <math.h>

#define B_ 2
#define C_ 256
#define FD_ 384
#define K_ 32
#define HW2 61440   // 192*320

typedef __attribute__((ext_vector_type(8))) short s8b;      // 8 bf16 (4 VGPRs)
typedef __attribute__((ext_vector_type(16))) float fvec16;  // MFMA 32x32 accumulator
typedef __attribute__((ext_vector_type(4))) float f4;       // LDS b128 unit

__device__ __forceinline__ unsigned short f2bf(float f) {
    unsigned int u = __builtin_bit_cast(unsigned int, f);
    u = (u + 0x7fffu + ((u >> 16) & 1u)) >> 16;
    return (unsigned short)u;
}

// ---------------- pre_proj: conv1x1 384->256 over 48x80 (2 outputs/block) ----------------
__global__ void k_preproj(const float* __restrict__ src, const float* __restrict__ w,
                          float* __restrict__ out) {
    __shared__ float w_s[2 * FD_];
    int bo = blockIdx.x;            // 256 blocks
    int b = bo >> 7, o = (bo & 127) * 2;
    int tid = threadIdx.x;
    for (int i = tid; i < 2 * FD_; i += 256) w_s[i] = w[o * FD_ + i];   // rows o, o+1 contiguous
    __syncthreads();
    float a0[15], a1[15];
#pragma unroll
    for (int k = 0; k < 15; k++) { a0[k] = 0.f; a1[k] = 0.f; }
    const float* sp = src + (long)b * FD_ * 3840;
    for (int c = 0; c < FD_; c++) {
        float wv0 = w_s[c];
        float wv1 = w_s[FD_ + c];
        const float* row = sp + (long)c * 3840;
#pragma unroll
        for (int k = 0; k < 15; k++) {
            float r = row[tid + k * 256];
            a0[k] += wv0 * r;
            a1[k] += wv1 * r;
        }
    }
    float* op = out + ((long)b * 256 + o) * 3840;
#pragma unroll
    for (int k = 0; k < 15; k++) op[tid + k * 256] = a0[k];
#pragma unroll
    for (int k = 0; k < 15; k++) op[3840 + tid + k * 256] = a1[k];
}

// ---------------- guidance downsample (tent, antialias) ----------------
__global__ void k_down_h(const float* __restrict__ in, float* __restrict__ out, int Ho, float s) {
    long idx = (long)blockIdx.x * 256 + threadIdx.x;
    long total = (long)B_ * 3 * Ho * 1280;
    if (idx >= total) return;
    int x = (int)(idx % 1280);
    long t1 = idx / 1280;
    int i = (int)(t1 % Ho);
    long t2 = t1 / Ho;
    int c = (int)(t2 % 3);
    int b = (int)(t2 / 3);
    float sf = (i + 0.5f) * s - 0.5f;
    int j0 = (int)floorf(sf - s) + 1;
    int j1 = (int)ceilf(sf + s) - 1;
    float acc = 0.f, wsum = 0.f;
    const float* ip = in + ((long)(b * 3 + c) * 768) * 1280 + x;
    for (int j = j0; j <= j1; j++) {
        if (j < 0 || j >= 768) continue;
        float wv = 1.f - fabsf((float)j - sf) / s;
        acc += wv * ip[(long)j * 1280];
        wsum += wv;
    }
    out[idx] = acc / wsum;
}

__global__ void k_down_w(const float* __restrict__ in, float* __restrict__ out, int Ho, int Wo, float s) {
    long idx = (long)blockIdx.x * 256 + threadIdx.x;
    long total = (long)B_ * 3 * Ho * Wo;
    if (idx >= total) return;
    int i = (int)(idx % Wo);
    long t1 = idx / Wo;
    int y = (int)(t1 % Ho);
    long t2 = t1 / Ho;
    int c = (int)(t2 % 3);
    int b = (int)(t2 / 3);
    float sf = (i + 0.5f) * s - 0.5f;
    int j0 = (int)floorf(sf - s) + 1;
    int j1 = (int)ceilf(sf + s) - 1;
    float acc = 0.f, wsum = 0.f;
    const float* ip = in + ((long)(b * 3 + c) * Ho + y) * 1280;
    for (int j = j0; j <= j1; j++) {
        if (j < 0 || j >= 1280) continue;
        float wv = 1.f - fabsf((float)j - sf) / s;
        acc += wv * ip[j];
        wsum += wv;
    }
    out[idx] = acc / wsum;
}

// ---------------- range projection MLP ----------------
__global__ void k_proj(const float* __restrict__ g, float* __restrict__ proj,
                       const float* __restrict__ w1, const float* __restrict__ b1,
                       const float* __restrict__ w2, const float* __restrict__ b2,
                       int HW) {
    __shared__ float w1_s[96], b1_s[32], w2_s[1024], b2_s[32];
    int tid = threadIdx.x;
    if (tid < 96) w1_s[tid] = w1[tid];
    if (tid < 32) { b1_s[tid] = b1[tid]; b2_s[tid] = b2[tid]; }
    for (int i = tid; i < 1024; i += 256) w2_s[i] = w2[i];
    __syncthreads();
    long idx = (long)blockIdx.x * 256 + tid;
    if (idx >= (long)B_ * HW) return;
    int b = (int)(idx / HW);
    int pix = (int)(idx % HW);
    const float* gp = g + (long)b * 3 * HW + pix;
    float g0 = gp[0], g1 = gp[HW], g2 = gp[2 * (long)HW];
    float hg[32];
#pragma unroll
    for (int k = 0; k < 32; k++) {
        float h = b1_s[k] + w1_s[k * 3] * g0 + w1_s[k * 3 + 1] * g1 + w1_s[k * 3 + 2] * g2;
        hg[k] = 0.5f * h * (1.f + erff(h * 0.70710678118654752f));
    }
    float* pp = proj + (long)b * 32 * HW + pix;
#pragma unroll
    for (int j = 0; j < 32; j++) {
        float a = b2_s[j];
#pragma unroll
        for (int k = 0; k < 32; k++) a += w2_s[j * 32 + k] * hg[k];
        pp[(long)j * HW] = a;
    }
}

// ======== k_ck: sims + softmax + spatial + renorm -> ck buffer [b][49][H][W] ========
__global__ __launch_bounds__(256) void k_ck(const float* __restrict__ proj,
                                            float* __restrict__ ckb,
                                            const float* __restrict__ temp,
                                            const float* __restrict__ sigma,
                                            int H, int W) {
    __shared__ __align__(16) float smem[9680];   // halo [484][20]

    int tid = threadIdx.x;
    int tx = tid & 15, ty = tid >> 4;
    int x0 = blockIdx.x * 16, y0 = blockIdx.y * 16;
    int b = blockIdx.z;

    float ck[49];
#pragma unroll
    for (int p = 0; p < 49; p++) ck[p] = 0.f;

    const float* pb = proj + (long)b * 32 * H * W;
    const f4* hs4 = (const f4*)smem;
#pragma unroll 1
    for (int pass = 0; pass < 2; pass++) {
        int k0 = pass * 16;
        for (int i = tid; i < 16 * 484; i += 256) {
            int k = i / 484;
            int rem = i - k * 484;
            int yy = rem / 22, xx = rem - yy * 22;
            int y = y0 - 3 + yy; y = y < 0 ? -y : (y >= H ? 2 * H - 2 - y : y);
            int x = x0 - 3 + xx; x = x < 0 ? -x : (x >= W ? 2 * W - 2 - x : x);
            smem[rem * 20 + k] = pb[((long)(k0 + k) * H + y) * W + x];
        }
        __syncthreads();
        int pc = ((ty + 3) * 22 + (tx + 3)) * 5;
        f4 c0 = hs4[pc + 0], c1 = hs4[pc + 1], c2 = hs4[pc + 2], c3 = hs4[pc + 3];
#pragma unroll
        for (int dy = 0; dy < 7; dy++) {
#pragma unroll
            for (int dx = 0; dx < 7; dx++) {
                int pn = ((ty + dy) * 22 + (tx + dx)) * 5;
                f4 s = hs4[pn + 0] * c0;
                s += hs4[pn + 1] * c1;
                s += hs4[pn + 2] * c2;
                s += hs4[pn + 3] * c3;
                ck[dy * 7 + dx] += (s.x + s.y) + (s.z + s.w);
            }
        }
        __syncthreads();
    }

    // softmax * spatial, renormalize (registers only)
    {
        float t = expf(temp[0]);
        t = fminf(fmaxf(t, 1e-4f), 1e4f);
        float m = -1e30f;
#pragma unroll
        for (int p = 0; p < 49; p++) { ck[p] *= t; m = fmaxf(m, ck[p]); }
        float ssum = 0.f;
#pragma unroll
        for (int p = 0; p < 49; p++) { ck[p] = expf(ck[p] - m); ssum += ck[p]; }
        float inv = 1.f / ssum;
        float sg = sigma[0];
        float dc = 1.f / (2.f * sg * sg);
        float csum = 0.f;
#pragma unroll
        for (int p = 0; p < 49; p++) {
            int dy = p / 7, dx = p % 7;
            float d0 = (dy - 3) / 3.f, d1 = (dx - 3) / 3.f;
            float sp = expf(-(d0 * d0 + d1 * d1) * dc);
            ck[p] = ck[p] * inv * sp;
            csum += ck[p];
        }
        float r = 1.f / fmaxf(csum, 1e-7f);
#pragma unroll
        for (int p = 0; p < 49; p++) ck[p] *= r;
    }

    // write out: [b][p][y][x], coalesced over tx
    long HWl = (long)H * W;
    float* cp = ckb + (long)b * 49 * HWl + (long)(y0 + ty) * W + (x0 + tx);
#pragma unroll
    for (int p = 0; p < 49; p++) cp[(long)p * HWl] = ck[p];
}

// ======== k_apply: bicubic-in-LDS + 49-tap apply (ck STREAMED from global) ========
// ck streamed 7-at-a-time per chunk (no cross-loop 49-reg live set). Natural VGPR
// demand measured 132 (round 6); (256,4) caps at 128 for 4 waves/SIMD — gap is only
// 4 regs so the allocator should trim, not wholesale-spill (watch FETCH_SIZE).
// LDS = 35808 B -> 4 blocks/CU at <=128 VGPR.
template <int CS>
__global__ __launch_bounds__(256, 4) void k_apply(const float* __restrict__ lo,
                                                  const float* ckb,
                                                  float* out,
                                                  int H, int W, int h, int w) {
    __shared__ __align__(16) float smem[8952];

    int tid = threadIdx.x;
    int tx = tid & 15, ty = tid >> 4;
    int x0 = blockIdx.x * 16, y0 = blockIdx.y * 16;
    int b = blockIdx.z / CS;
    int c_base = (blockIdx.z % CS) * (256 / CS);

    long HWl = (long)H * W;
    const float* cp = ckb + (long)b * 49 * HWl + (long)(y0 + ty) * W + (x0 + tx);

    // ---- contiguous 22-window covering all reflect-padded taps ----
    int ws_y = y0 - 3; if (ws_y < 0) ws_y = 0; if (ws_y > H - 22) ws_y = H - 22;
    int ws_x = x0 - 3; if (ws_x < 0) ws_x = 0; if (ws_x > W - 22) ws_x = W - 22;
    int ls_y = (ws_y >> 1) - 2, ls_x = (ws_x >> 1) - 2;
    int ry[7], rx[7];   // pre-scaled LDS offsets: row*45, col*2
#pragma unroll
    for (int d = 0; d < 7; d++) {
        int v = y0 + ty + d - 3; v = v < 0 ? -v : (v >= H ? 2 * H - 2 - v : v);
        ry[d] = (v - ws_y) * 45;
        int u = x0 + tx + d - 3; u = u < 0 ? -u : (u >= W ? 2 * W - 2 - u : u);
        rx[d] = (u - ws_x) * 2;
    }

    // staging coords for lo tile (per-element clamp handles bicubic edge-clamp)
    int lrow = ls_y + ty; lrow = lrow < 0 ? 0 : (lrow >= h ? h - 1 : lrow);
    int lcol = ls_x + tx; lcol = lcol < 0 ? 0 : (lcol >= w ? w - 1 : lcol);

    // f4 tiles (channel-packed, 4 ch per f4, 2 groups = 8 ch per chunk)
    f4* lo4  = (f4*)smem;                  // [16 rows][33 f4]
    f4* tmp4 = (f4*)(smem + 2112);         // [16 rows][45 f4]
    f4* hr4  = (f4*)(smem + 2112 + 2880);  // [22 rows][45 f4]

    long hw = (long)h * w;

    const int nchunk = (256 / CS) / 8;
#pragma unroll 1
    for (int cc = 0; cc < nchunk; cc++) {
        int c0 = c_base + cc * 8;
        // stage lo: gather 8 channels into 2 f4 per thread
        const float* lp = lo + (((long)b * 256 + c0) * h + lrow) * w + lcol;
        f4 va, vb;
        va.x = lp[0];      va.y = lp[hw];     va.z = lp[2 * hw]; va.w = lp[3 * hw];
        vb.x = lp[4 * hw]; vb.y = lp[5 * hw]; vb.z = lp[6 * hw]; vb.w = lp[7 * hw];
        lo4[ty * 33 + tx * 2 + 0] = va;
        lo4[ty * 33 + tx * 2 + 1] = vb;
        __syncthreads();

        // horizontal bicubic: tmp [16 lo-rows][22 hr-cols][2 g]  (704 f4)
#pragma unroll
        for (int it = 0; it < 3; it++) {
            int e = tid + it * 256;
            if (e < 704) {
                int g = e & 1, rem = e >> 1;
                int j = rem / 22, Xp = rem - j * 22;
                int X = ws_x + Xp;
                int ix = (X >> 1) - ls_x;
                const f4* lr = lo4 + j * 33 + g;
                f4 v;
                if (X & 1)
                    v = -0.10546875f * lr[(ix - 1) * 2] + 0.87890625f * lr[ix * 2] + 0.26171875f * lr[(ix + 1) * 2] - 0.03515625f * lr[(ix + 2) * 2];
                else
                    v = -0.03515625f * lr[(ix - 2) * 2] + 0.26171875f * lr[(ix - 1) * 2] + 0.87890625f * lr[ix * 2] - 0.10546875f * lr[(ix + 1) * 2];
                tmp4[j * 45 + Xp * 2 + g] = v;
            }
        }
        __syncthreads();

        // vertical bicubic: hr [22 rows][22 cols][2 g]  (968 f4)
#pragma unroll
        for (int it = 0; it < 4; it++) {
            int e = tid + it * 256;
            if (e < 968) {
                int g = e & 1, rem = e >> 1;
                int i = rem / 22, Xp = rem - i * 22;
                int Y = ws_y + i;
                int jy = (Y >> 1) - ls_y;
                const f4* tc = tmp4 + Xp * 2 + g;
                f4 v;
                if (Y & 1)
                    v = -0.10546875f * tc[(jy - 1) * 45] + 0.87890625f * tc[jy * 45] + 0.26171875f * tc[(jy + 1) * 45] - 0.03515625f * tc[(jy + 2) * 45];
                else
                    v = -0.03515625f * tc[(jy - 2) * 45] + 0.26171875f * tc[(jy - 1) * 45] + 0.87890625f * tc[jy * 45] - 0.10546875f * tc[(jy + 1) * 45];
                hr4[i * 45 + Xp * 2 + g] = v;
            }
        }
        __syncthreads();

        // apply 49 taps, both channel-groups per tap-row; ck streamed 7-at-a-time
        f4 acc0 = (f4)(0.f), acc1 = (f4)(0.f);
#pragma unroll
        for (int dy = 0; dy < 7; dy++) {
            float c_[7];
#pragma unroll
            for (int dx = 0; dx < 7; dx++) c_[dx] = cp[(long)(dy * 7 + dx) * HWl];
            const f4* hrow = hr4 + ry[dy];
#pragma unroll
            for (int dx = 0; dx < 7; dx++) {
                acc0 += c_[dx] * hrow[rx[dx]];
                acc1 += c_[dx] * hrow[rx[dx] + 1];
            }
        }
        float* op = out + (((long)b * 256 + c0) * H + (y0 + ty)) * W + (x0 + tx);
        op[0]        = acc0.x;
        op[HWl]      = acc0.y;
        op[2 * HWl]  = acc0.z;
        op[3 * HWl]  = acc0.w;
        op[4 * HWl]  = acc1.x;
        op[5 * HWl]  = acc1.y;
        op[6 * HWl]  = acc1.z;
        op[7 * HWl]  = acc1.w;
        // no trailing barrier: next chunk's stage-sync orders apply reads vs later writes
    }
}

// ---------------- prep: pack W[o][c] fp32 -> bf16 MFMA A-fragment order ----------------
__global__ void k_prepw(const float* __restrict__ w, unsigned short* __restrict__ wf) {
    int blk = blockIdx.x;           // mt*16+ks, 128 blocks
    int lane = threadIdx.x;         // 64
    int mt = blk >> 4, ks = blk & 15;
    int o = mt * 32 + (lane & 31);
    int c = ks * 16 + (lane >> 5) * 8;
    const float* wp = w + (long)o * 256 + c;
    float4 v0 = *(const float4*)wp;
    float4 v1 = *(const float4*)(wp + 4);
    unsigned short* dst = wf + ((long)(blk * 64 + lane)) * 8;
    unsigned int r0 = f2bf(v0.x) | ((unsigned int)f2bf(v0.y) << 16);
    unsigned int r1 = f2bf(v0.z) | ((unsigned int)f2bf(v0.w) << 16);
    unsigned int r2 = f2bf(v1.x) | ((unsigned int)f2bf(v1.y) << 16);
    unsigned int r3 = f2bf(v1.z) | ((unsigned int)f2bf(v1.w) << 16);
    uint4 pk = {r0, r1, r2, r3};
    *(uint4*)dst = pk;
}

// ---------------- MFMA GEMM: y = W @ x (+ GN-fold / + residual + GN-stat partials) ----
// RESID epilogue also accumulates per-group (sum, sumsq) partials of the POST-residual
// values: group = mt*4 + (r>>2) (exact: row = (r&3)+8*(r>>2)+4*hh, so row>>3 == r>>2).
// Per-block partials -> part[(b*32+g)*960 + tile][2]; k_gnred2 reduces over 960 tiles.
// This removes the separate 126 MB k_gnpart pass.
#define LDK 264
template <bool GN, bool RESID>
__global__ __launch_bounds__(256) void k_gemm256(float* __restrict__ x,
                                                 const unsigned short* __restrict__ wf,
                                                 const float* __restrict__ stats,
                                                 const float* __restrict__ gn_w,
                                                 const float* __restrict__ gn_b,
                                                 float* __restrict__ part) {
    __shared__ unsigned short xs[64 * LDK];
    __shared__ float scl_s[256], sh_s[256];
    __shared__ float gs[64];
    int tid = threadIdx.x;
    int b = blockIdx.y;
    int pix0 = blockIdx.x * 64;
    float* xb = x + (long)b * 256 * HW2;

    if (RESID && tid < 64) gs[tid] = 0.f;

    if (GN) {
        int c = tid;
        int g = c >> 3;
        float mean = stats[(b * 32 + g) * 2];
        float rstd = stats[(b * 32 + g) * 2 + 1];
        float s = rstd * gn_w[c];
        scl_s[c] = s;
        sh_s[c] = gn_b[c] - mean * s;
        __syncthreads();
    }

#pragma unroll
    for (int it = 0; it < 4; it++) {
        int c0 = ((tid >> 4) << 2) + it * 64;
        int px = (tid & 15) << 2;
        const float* gp = xb + (long)c0 * HW2 + pix0 + px;
        float4 v0 = *(const float4*)gp;
        float4 v1 = *(const float4*)(gp + HW2);
        float4 v2 = *(const float4*)(gp + 2 * HW2);
        float4 v3 = *(const float4*)(gp + 3 * HW2);
        if (GN) {
            float s0 = scl_s[c0], h0 = sh_s[c0];
            float s1 = scl_s[c0 + 1], h1 = sh_s[c0 + 1];
            float s2 = scl_s[c0 + 2], h2 = sh_s[c0 + 2];
            float s3 = scl_s[c0 + 3], h3 = sh_s[c0 + 3];
            v0.x = v0.x * s0 + h0; v0.y = v0.y * s0 + h0; v0.z = v0.z * s0 + h0; v0.w = v0.w * s0 + h0;
            v1.x = v1.x * s1 + h1; v1.y = v1.y * s1 + h1; v1.z = v1.z * s1 + h1; v1.w = v1.w * s1 + h1;
            v2.x = v2.x * s2 + h2; v2.y = v2.y * s2 + h2; v2.z = v2.z * s2 + h2; v2.w = v2.w * s2 + h2;
            v3.x = v3.x * s3 + h3; v3.y = v3.y * s3 + h3; v3.z = v3.z * s3 + h3; v3.w = v3.w * s3 + h3;
        }
        float p0[4] = {v0.x, v0.y, v0.z, v0.w};
        float p1[4] = {v1.x, v1.y, v1.z, v1.w};
        float p2[4] = {v2.x, v2.y, v2.z, v2.w};
        float p3[4] = {v3.x, v3.y, v3.z, v3.w};
#pragma unroll
        for (int p = 0; p < 4; p++) {
            ushort4 u;
            u.x = f2bf(p0[p]); u.y = f2bf(p1[p]); u.z = f2bf(p2[p]); u.w = f2bf(p3[p]);
            *(ushort4*)&xs[(px + p) * LDK + c0] = u;
        }
    }
    __syncthreads();

    int lane = tid & 63, wv = tid >> 6;
    fvec16 acc[2][2];
#pragma unroll
    for (int mi = 0; mi < 2; mi++)
#pragma unroll
        for (int ni = 0; ni < 2; ni++)
            acc[mi][ni] = (fvec16)(0.f);

    int n_in = lane & 31;
    int koff = (lane >> 5) * 8;
#pragma unroll
    for (int ks = 0; ks < 16; ks++) {
        s8b a0 = *(const s8b*)(wf + ((long)(((wv * 2 + 0) * 16 + ks) * 64 + lane)) * 8);
        s8b a1 = *(const s8b*)(wf + ((long)(((wv * 2 + 1) * 16 + ks) * 64 + lane)) * 8);
        s8b b0 = *(const s8b*)&xs[(0 + n_in) * LDK + ks * 16 + koff];
        s8b b1 = *(const s8b*)&xs[(32 + n_in) * LDK + ks * 16 + koff];
        acc[0][0] = __builtin_amdgcn_mfma_f32_32x32x16_bf16(a0, b0, acc[0][0], 0, 0, 0);
        acc[0][1] = __builtin_amdgcn_mfma_f32_32x32x16_bf16(a0, b1, acc[0][1], 0, 0, 0);
        acc[1][0] = __builtin_amdgcn_mfma_f32_32x32x16_bf16(a1, b0, acc[1][0], 0, 0, 0);
        acc[1][1] = __builtin_amdgcn_mfma_f32_32x32x16_bf16(a1, b1, acc[1][1], 0, 0, 0);
    }

    int hh = lane >> 5;
    float ls[2][4], lq[2][4];
    if (RESID) {
#pragma unroll
        for (int mi = 0; mi < 2; mi++)
#pragma unroll
            for (int gq = 0; gq < 4; gq++) { ls[mi][gq] = 0.f; lq[mi][gq] = 0.f; }
    }
#pragma unroll
    for (int mi = 0; mi < 2; mi++) {
        int mt = wv * 2 + mi;
#pragma unroll
        for (int ni = 0; ni < 2; ni++) {
            int pix = pix0 + ni * 32 + n_in;
#pragma unroll
            for (int r = 0; r < 16; r++) {
                int row = (r & 3) + 8 * (r >> 2) + 4 * hh;
                long addr = (long)(mt * 32 + row) * HW2 + pix;
                if (RESID) {
                    float v = xb[addr] + 0.1f * acc[mi][ni][r];
                    xb[addr] = v;
                    ls[mi][r >> 2] += v;
                    lq[mi][r >> 2] += v * v;
                } else {
                    xb[addr] = acc[mi][ni][r];
                }
            }
        }
    }
    if (RESID) {
#pragma unroll
        for (int mi = 0; mi < 2; mi++)
#pragma unroll
            for (int gq = 0; gq < 4; gq++) {
                int g = (wv * 2 + mi) * 4 + gq;
                atomicAdd(&gs[g * 2], ls[mi][gq]);
                atomicAdd(&gs[g * 2 + 1], lq[mi][gq]);
            }
        __syncthreads();
        if (tid < 64) {
            int g = tid >> 1, which = tid & 1;
            part[((long)(b * 32 + g) * 960 + blockIdx.x) * 2 + which] = gs[tid];
        }
    }
}

// ---------------- GroupNorm stats reduce: 960 tile-partials -> mean/rstd ----------------
__global__ void k_gnred2(const float* __restrict__ part, float* __restrict__ stats) {
    int t = threadIdx.x;  // 64 = b*32+g
    const float* p = part + (long)t * 960 * 2;
    double s = 0.0, q = 0.0;
    for (int i = 0; i < 960; i++) {
        s += p[2 * i];
        q += p[2 * i + 1];
    }
    double N = 8.0 * HW2;
    double mean = s / N;
    double var = q / N - mean * mean;
    stats[t * 2] = (float)mean;
    stats[t * 2 + 1] = (float)(1.0 / sqrt(var + 1e-5));
}

extern "C" void kernel_launch(void* const* d_in, const int* in_sizes, int n_in,
                              void* d_out, int out_size, void* d_ws, size_t ws_size,
                              hipStream_t stream) {
    const float* src      = (const float*)d_in[0];
    const float* guidance = (const float*)d_in[1];
    const float* pre_w    = (const float*)d_in[2];
    const float* rp1_w1   = (const float*)d_in[3];
    const float* rp1_b1   = (const float*)d_in[4];
    const float* rp1_w2   = (const float*)d_in[5];
    const float* rp1_b2   = (const float*)d_in[6];
    const float* temp1    = (const float*)d_in[7];
    const float* sigma1   = (const float*)d_in[8];
    const float* rp2_w1   = (const float*)d_in[9];
    const float* rp2_b1   = (const float*)d_in[10];
    const float* rp2_w2   = (const float*)d_in[11];
    const float* rp2_b2   = (const float*)d_in[12];
    const float* temp2    = (const float*)d_in[13];
    const float* sigma2   = (const float*)d_in[14];
    const float* fixup_w  = (const float*)d_in[15];
    const float* gn_w     = (const float*)d_in[16];
    const float* gn_b     = (const float*)d_in[17];
    const float* proj_w   = (const float*)d_in[18];
    float* out = (float*)d_out;

    // ---- workspace arena ----
    char* ws = (char*)d_ws;
    size_t off = 0;
    auto alloc = [&](size_t bytes) { size_t o = off; off = (off + bytes + 255) & ~(size_t)255; return o; };
    float* gdown  = (float*)(ws + alloc((size_t)2 * 3 * 192 * 1280 * 4));
    float* gbuf   = (float*)(ws + alloc((size_t)2 * 3 * 192 * 320 * 4));
    float* projb  = (float*)(ws + alloc((size_t)2 * 32 * 192 * 320 * 4));
    float* x1     = (float*)(ws + alloc((size_t)2 * 256 * 48 * 80 * 4));
    float* out1   = (float*)(ws + alloc((size_t)2 * 256 * 96 * 160 * 4));
    float* ckbuf  = (float*)(ws + alloc((size_t)2 * 49 * 192 * 320 * 4));   // reused across steps
    unsigned short* wfFix  = (unsigned short*)(ws + alloc(65536 * 2));
    unsigned short* wfProj = (unsigned short*)(ws + alloc(65536 * 2));
    float* gpart  = (float*)(ws + alloc((size_t)64 * 960 * 2 * 4));
    float* stats  = (float*)(ws + alloc(64 * 2 * 4));

    // weight prep (bf16 MFMA fragment order)
    k_prepw<<<128, 64, 0, stream>>>(fixup_w, wfFix);
    k_prepw<<<128, 64, 0, stream>>>(proj_w, wfProj);

    // pre-projection 384->256 (2 outputs per block)
    k_preproj<<<256, 256, 0, stream>>>(src, pre_w, x1);

    // ---- JBU step 1: 48x80 -> 96x160 ----
    {
        const int H = 96, W = 160, HW = H * W;
        k_down_h<<<(2 * 3 * H * 1280) / 256, 256, 0, stream>>>(guidance, gdown, H, 8.f);
        k_down_w<<<(2 * 3 * HW + 255) / 256, 256, 0, stream>>>(gdown, gbuf, H, W, 8.f);
        k_proj<<<(2 * HW + 255) / 256, 256, 0, stream>>>(gbuf, projb, rp1_w1, rp1_b1, rp1_w2, rp1_b2, HW);
        k_ck<<<dim3(W / 16, H / 16, 2), 256, 0, stream>>>(projb, ckbuf, temp1, sigma1, H, W);
        k_apply<4><<<dim3(W / 16, H / 16, 2 * 4), 256, 0, stream>>>(x1, ckbuf, out1, H, W, 48, 80);
    }

    // ---- JBU step 2: 96x160 -> 192x320 ----
    {
        const int H = 192, W = 320, HW = H * W;
        k_down_h<<<(2 * 3 * H * 1280) / 256, 256, 0, stream>>>(guidance, gdown, H, 4.f);
        k_down_w<<<(2 * 3 * HW + 255) / 256, 256, 0, stream>>>(gdown, gbuf, H, W, 4.f);
        k_proj<<<(2 * HW + 255) / 256, 256, 0, stream>>>(gbuf, projb, rp2_w1, rp2_b1, rp2_w2, rp2_b2, HW);
        k_ck<<<dim3(W / 16, H / 16, 2), 256, 0, stream>>>(projb, ckbuf, temp2, sigma2, H, W);
        k_apply<4><<<dim3(W / 16, H / 16, 2 * 4), 256, 0, stream>>>(out1, ckbuf, out, H, W, 96, 160);
    }

    // ---- fixup residual (+ fused GN-stat partials): out = out + 0.1 * W @ out ----
    k_gemm256<false, true><<<dim3(960, 2), 256, 0, stream>>>(out, wfFix, nullptr, nullptr, nullptr, gpart);
    // ---- GroupNorm stats reduce ----
    k_gnred2<<<1, 64, 0, stream>>>(gpart, stats);
    // ---- GN affine + final projection (MFMA, in-place) ----
    k_gemm256<true, false><<<dim3(960, 2), 256, 0, stream>>>(out, wfProj, stats, gn_w, gn_b, nullptr);
}

// Round 8
// 965.099 us; speedup vs baseline: 1.5227x; 1.5227x over previous
//
#include <hip/hip_runtime.h>
#include <math.h>

#define B_ 2
#define C_ 256
#define FD_ 384
#define K_ 32
#define HW2 61440   // 192*320

typedef __attribute__((ext_vector_type(8))) short s8b;      // 8 bf16 (4 VGPRs)
typedef __attribute__((ext_vector_type(16))) float fvec16;  // MFMA 32x32 accumulator
typedef __attribute__((ext_vector_type(4))) float f4;       // LDS b128 unit

__device__ __forceinline__ unsigned short f2bf(float f) {
    unsigned int u = __builtin_bit_cast(unsigned int, f);
    u = (u + 0x7fffu + ((u >> 16) & 1u)) >> 16;
    return (unsigned short)u;
}

// ---------------- pre_proj: conv1x1 384->256 over 48x80 (2 outputs/block) ----------------
__global__ void k_preproj(const float* __restrict__ src, const float* __restrict__ w,
                          float* __restrict__ out) {
    __shared__ float w_s[2 * FD_];
    int bo = blockIdx.x;            // 256 blocks
    int b = bo >> 7, o = (bo & 127) * 2;
    int tid = threadIdx.x;
    for (int i = tid; i < 2 * FD_; i += 256) w_s[i] = w[o * FD_ + i];   // rows o, o+1 contiguous
    __syncthreads();
    float a0[15], a1[15];
#pragma unroll
    for (int k = 0; k < 15; k++) { a0[k] = 0.f; a1[k] = 0.f; }
    const float* sp = src + (long)b * FD_ * 3840;
    for (int c = 0; c < FD_; c++) {
        float wv0 = w_s[c];
        float wv1 = w_s[FD_ + c];
        const float* row = sp + (long)c * 3840;
#pragma unroll
        for (int k = 0; k < 15; k++) {
            float r = row[tid + k * 256];
            a0[k] += wv0 * r;
            a1[k] += wv1 * r;
        }
    }
    float* op = out + ((long)b * 256 + o) * 3840;
#pragma unroll
    for (int k = 0; k < 15; k++) op[tid + k * 256] = a0[k];
#pragma unroll
    for (int k = 0; k < 15; k++) op[3840 + tid + k * 256] = a1[k];
}

// ---------------- guidance downsample (tent, antialias) ----------------
__global__ void k_down_h(const float* __restrict__ in, float* __restrict__ out, int Ho, float s) {
    long idx = (long)blockIdx.x * 256 + threadIdx.x;
    long total = (long)B_ * 3 * Ho * 1280;
    if (idx >= total) return;
    int x = (int)(idx % 1280);
    long t1 = idx / 1280;
    int i = (int)(t1 % Ho);
    long t2 = t1 / Ho;
    int c = (int)(t2 % 3);
    int b = (int)(t2 / 3);
    float sf = (i + 0.5f) * s - 0.5f;
    int j0 = (int)floorf(sf - s) + 1;
    int j1 = (int)ceilf(sf + s) - 1;
    float acc = 0.f, wsum = 0.f;
    const float* ip = in + ((long)(b * 3 + c) * 768) * 1280 + x;
    for (int j = j0; j <= j1; j++) {
        if (j < 0 || j >= 768) continue;
        float wv = 1.f - fabsf((float)j - sf) / s;
        acc += wv * ip[(long)j * 1280];
        wsum += wv;
    }
    out[idx] = acc / wsum;
}

__global__ void k_down_w(const float* __restrict__ in, float* __restrict__ out, int Ho, int Wo, float s) {
    long idx = (long)blockIdx.x * 256 + threadIdx.x;
    long total = (long)B_ * 3 * Ho * Wo;
    if (idx >= total) return;
    int i = (int)(idx % Wo);
    long t1 = idx / Wo;
    int y = (int)(t1 % Ho);
    long t2 = t1 / Ho;
    int c = (int)(t2 % 3);
    int b = (int)(t2 / 3);
    float sf = (i + 0.5f) * s - 0.5f;
    int j0 = (int)floorf(sf - s) + 1;
    int j1 = (int)ceilf(sf + s) - 1;
    float acc = 0.f, wsum = 0.f;
    const float* ip = in + ((long)(b * 3 + c) * Ho + y) * 1280;
    for (int j = j0; j <= j1; j++) {
        if (j < 0 || j >= 1280) continue;
        float wv = 1.f - fabsf((float)j - sf) / s;
        acc += wv * ip[j];
        wsum += wv;
    }
    out[idx] = acc / wsum;
}

// ---------------- range projection MLP ----------------
__global__ void k_proj(const float* __restrict__ g, float* __restrict__ proj,
                       const float* __restrict__ w1, const float* __restrict__ b1,
                       const float* __restrict__ w2, const float* __restrict__ b2,
                       int HW) {
    __shared__ float w1_s[96], b1_s[32], w2_s[1024], b2_s[32];
    int tid = threadIdx.x;
    if (tid < 96) w1_s[tid] = w1[tid];
    if (tid < 32) { b1_s[tid] = b1[tid]; b2_s[tid] = b2[tid]; }
    for (int i = tid; i < 1024; i += 256) w2_s[i] = w2[i];
    __syncthreads();
    long idx = (long)blockIdx.x * 256 + tid;
    if (idx >= (long)B_ * HW) return;
    int b = (int)(idx / HW);
    int pix = (int)(idx % HW);
    const float* gp = g + (long)b * 3 * HW + pix;
    float g0 = gp[0], g1 = gp[HW], g2 = gp[2 * (long)HW];
    float hg[32];
#pragma unroll
    for (int k = 0; k < 32; k++) {
        float h = b1_s[k] + w1_s[k * 3] * g0 + w1_s[k * 3 + 1] * g1 + w1_s[k * 3 + 2] * g2;
        hg[k] = 0.5f * h * (1.f + erff(h * 0.70710678118654752f));
    }
    float* pp = proj + (long)b * 32 * HW + pix;
#pragma unroll
    for (int j = 0; j < 32; j++) {
        float a = b2_s[j];
#pragma unroll
        for (int k = 0; k < 32; k++) a += w2_s[j * 32 + k] * hg[k];
        pp[(long)j * HW] = a;
    }
}

// ======== k_ck: sims + softmax + spatial + renorm -> ck buffer [b][49][H][W] ========
__global__ __launch_bounds__(256) void k_ck(const float* __restrict__ proj,
                                            float* __restrict__ ckb,
                                            const float* __restrict__ temp,
                                            const float* __restrict__ sigma,
                                            int H, int W) {
    __shared__ __align__(16) float smem[9680];   // halo [484][20]

    int tid = threadIdx.x;
    int tx = tid & 15, ty = tid >> 4;
    int x0 = blockIdx.x * 16, y0 = blockIdx.y * 16;
    int b = blockIdx.z;

    float ck[49];
#pragma unroll
    for (int p = 0; p < 49; p++) ck[p] = 0.f;

    const float* pb = proj + (long)b * 32 * H * W;
    const f4* hs4 = (const f4*)smem;
#pragma unroll 1
    for (int pass = 0; pass < 2; pass++) {
        int k0 = pass * 16;
        for (int i = tid; i < 16 * 484; i += 256) {
            int k = i / 484;
            int rem = i - k * 484;
            int yy = rem / 22, xx = rem - yy * 22;
            int y = y0 - 3 + yy; y = y < 0 ? -y : (y >= H ? 2 * H - 2 - y : y);
            int x = x0 - 3 + xx; x = x < 0 ? -x : (x >= W ? 2 * W - 2 - x : x);
            smem[rem * 20 + k] = pb[((long)(k0 + k) * H + y) * W + x];
        }
        __syncthreads();
        int pc = ((ty + 3) * 22 + (tx + 3)) * 5;
        f4 c0 = hs4[pc + 0], c1 = hs4[pc + 1], c2 = hs4[pc + 2], c3 = hs4[pc + 3];
#pragma unroll
        for (int dy = 0; dy < 7; dy++) {
#pragma unroll
            for (int dx = 0; dx < 7; dx++) {
                int pn = ((ty + dy) * 22 + (tx + dx)) * 5;
                f4 s = hs4[pn + 0] * c0;
                s += hs4[pn + 1] * c1;
                s += hs4[pn + 2] * c2;
                s += hs4[pn + 3] * c3;
                ck[dy * 7 + dx] += (s.x + s.y) + (s.z + s.w);
            }
        }
        __syncthreads();
    }

    // softmax * spatial, renormalize (registers only)
    {
        float t = expf(temp[0]);
        t = fminf(fmaxf(t, 1e-4f), 1e4f);
        float m = -1e30f;
#pragma unroll
        for (int p = 0; p < 49; p++) { ck[p] *= t; m = fmaxf(m, ck[p]); }
        float ssum = 0.f;
#pragma unroll
        for (int p = 0; p < 49; p++) { ck[p] = expf(ck[p] - m); ssum += ck[p]; }
        float inv = 1.f / ssum;
        float sg = sigma[0];
        float dc = 1.f / (2.f * sg * sg);
        float csum = 0.f;
#pragma unroll
        for (int p = 0; p < 49; p++) {
            int dy = p / 7, dx = p % 7;
            float d0 = (dy - 3) / 3.f, d1 = (dx - 3) / 3.f;
            float sp = expf(-(d0 * d0 + d1 * d1) * dc);
            ck[p] = ck[p] * inv * sp;
            csum += ck[p];
        }
        float r = 1.f / fmaxf(csum, 1e-7f);
#pragma unroll
        for (int p = 0; p < 49; p++) ck[p] *= r;
    }

    // write out: [b][p][y][x], coalesced over tx
    long HWl = (long)H * W;
    float* cp = ckb + (long)b * 49 * HWl + (long)(y0 + ty) * W + (x0 + tx);
#pragma unroll
    for (int p = 0; p < 49; p++) cp[(long)p * HWl] = ck[p];
}

// ======== k_apply: bicubic-in-LDS + 49-tap apply (ck STREAMED from global) ========
// ck streamed 7-at-a-time per chunk (no cross-loop 49-reg live set).
// PLAIN __launch_bounds__(256) — DO NOT add a min-waves arg: every cap tried
// (128/168 on fused, 128 on split) collapsed the allocator to 64-84 VGPR with
// wholesale ck-spill to scratch (FETCH 0.4->1-3 GB, 2-6x slower). Measured good
// point: 132 VGPR, 244us @ step2. LDS = 35808 B.
template <int CS>
__global__ __launch_bounds__(256) void k_apply(const float* __restrict__ lo,
                                               const float* ckb,
                                               float* out,
                                               int H, int W, int h, int w) {
    __shared__ __align__(16) float smem[8952];

    int tid = threadIdx.x;
    int tx = tid & 15, ty = tid >> 4;
    int x0 = blockIdx.x * 16, y0 = blockIdx.y * 16;
    int b = blockIdx.z / CS;
    int c_base = (blockIdx.z % CS) * (256 / CS);

    long HWl = (long)H * W;
    const float* cp = ckb + (long)b * 49 * HWl + (long)(y0 + ty) * W + (x0 + tx);

    // ---- contiguous 22-window covering all reflect-padded taps ----
    int ws_y = y0 - 3; if (ws_y < 0) ws_y = 0; if (ws_y > H - 22) ws_y = H - 22;
    int ws_x = x0 - 3; if (ws_x < 0) ws_x = 0; if (ws_x > W - 22) ws_x = W - 22;
    int ls_y = (ws_y >> 1) - 2, ls_x = (ws_x >> 1) - 2;
    int ry[7], rx[7];   // pre-scaled LDS offsets: row*45, col*2
#pragma unroll
    for (int d = 0; d < 7; d++) {
        int v = y0 + ty + d - 3; v = v < 0 ? -v : (v >= H ? 2 * H - 2 - v : v);
        ry[d] = (v - ws_y) * 45;
        int u = x0 + tx + d - 3; u = u < 0 ? -u : (u >= W ? 2 * W - 2 - u : u);
        rx[d] = (u - ws_x) * 2;
    }

    // staging coords for lo tile (per-element clamp handles bicubic edge-clamp)
    int lrow = ls_y + ty; lrow = lrow < 0 ? 0 : (lrow >= h ? h - 1 : lrow);
    int lcol = ls_x + tx; lcol = lcol < 0 ? 0 : (lcol >= w ? w - 1 : lcol);

    // f4 tiles (channel-packed, 4 ch per f4, 2 groups = 8 ch per chunk)
    f4* lo4  = (f4*)smem;                  // [16 rows][33 f4]
    f4* tmp4 = (f4*)(smem + 2112);         // [16 rows][45 f4]
    f4* hr4  = (f4*)(smem + 2112 + 2880);  // [22 rows][45 f4]

    long hw = (long)h * w;

    const int nchunk = (256 / CS) / 8;
#pragma unroll 1
    for (int cc = 0; cc < nchunk; cc++) {
        int c0 = c_base + cc * 8;
        // stage lo: gather 8 channels into 2 f4 per thread
        const float* lp = lo + (((long)b * 256 + c0) * h + lrow) * w + lcol;
        f4 va, vb;
        va.x = lp[0];      va.y = lp[hw];     va.z = lp[2 * hw]; va.w = lp[3 * hw];
        vb.x = lp[4 * hw]; vb.y = lp[5 * hw]; vb.z = lp[6 * hw]; vb.w = lp[7 * hw];
        lo4[ty * 33 + tx * 2 + 0] = va;
        lo4[ty * 33 + tx * 2 + 1] = vb;
        __syncthreads();

        // horizontal bicubic: tmp [16 lo-rows][22 hr-cols][2 g]  (704 f4)
#pragma unroll
        for (int it = 0; it < 3; it++) {
            int e = tid + it * 256;
            if (e < 704) {
                int g = e & 1, rem = e >> 1;
                int j = rem / 22, Xp = rem - j * 22;
                int X = ws_x + Xp;
                int ix = (X >> 1) - ls_x;
                const f4* lr = lo4 + j * 33 + g;
                f4 v;
                if (X & 1)
                    v = -0.10546875f * lr[(ix - 1) * 2] + 0.87890625f * lr[ix * 2] + 0.26171875f * lr[(ix + 1) * 2] - 0.03515625f * lr[(ix + 2) * 2];
                else
                    v = -0.03515625f * lr[(ix - 2) * 2] + 0.26171875f * lr[(ix - 1) * 2] + 0.87890625f * lr[ix * 2] - 0.10546875f * lr[(ix + 1) * 2];
                tmp4[j * 45 + Xp * 2 + g] = v;
            }
        }
        __syncthreads();

        // vertical bicubic: hr [22 rows][22 cols][2 g]  (968 f4)
#pragma unroll
        for (int it = 0; it < 4; it++) {
            int e = tid + it * 256;
            if (e < 968) {
                int g = e & 1, rem = e >> 1;
                int i = rem / 22, Xp = rem - i * 22;
                int Y = ws_y + i;
                int jy = (Y >> 1) - ls_y;
                const f4* tc = tmp4 + Xp * 2 + g;
                f4 v;
                if (Y & 1)
                    v = -0.10546875f * tc[(jy - 1) * 45] + 0.87890625f * tc[jy * 45] + 0.26171875f * tc[(jy + 1) * 45] - 0.03515625f * tc[(jy + 2) * 45];
                else
                    v = -0.03515625f * tc[(jy - 2) * 45] + 0.26171875f * tc[(jy - 1) * 45] + 0.87890625f * tc[jy * 45] - 0.10546875f * tc[(jy + 1) * 45];
                hr4[i * 45 + Xp * 2 + g] = v;
            }
        }
        __syncthreads();

        // apply 49 taps, both channel-groups per tap-row; ck streamed 7-at-a-time
        f4 acc0 = (f4)(0.f), acc1 = (f4)(0.f);
#pragma unroll
        for (int dy = 0; dy < 7; dy++) {
            float c_[7];
#pragma unroll
            for (int dx = 0; dx < 7; dx++) c_[dx] = cp[(long)(dy * 7 + dx) * HWl];
            const f4* hrow = hr4 + ry[dy];
#pragma unroll
            for (int dx = 0; dx < 7; dx++) {
                acc0 += c_[dx] * hrow[rx[dx]];
                acc1 += c_[dx] * hrow[rx[dx] + 1];
            }
        }
        float* op = out + (((long)b * 256 + c0) * H + (y0 + ty)) * W + (x0 + tx);
        op[0]        = acc0.x;
        op[HWl]      = acc0.y;
        op[2 * HWl]  = acc0.z;
        op[3 * HWl]  = acc0.w;
        op[4 * HWl]  = acc1.x;
        op[5 * HWl]  = acc1.y;
        op[6 * HWl]  = acc1.z;
        op[7 * HWl]  = acc1.w;
        // no trailing barrier: next chunk's stage-sync orders apply reads vs later writes
    }
}

// ---------------- prep: pack W[o][c] fp32 -> bf16 MFMA A-fragment order ----------------
__global__ void k_prepw(const float* __restrict__ w, unsigned short* __restrict__ wf) {
    int blk = blockIdx.x;           // mt*16+ks, 128 blocks
    int lane = threadIdx.x;         // 64
    int mt = blk >> 4, ks = blk & 15;
    int o = mt * 32 + (lane & 31);
    int c = ks * 16 + (lane >> 5) * 8;
    const float* wp = w + (long)o * 256 + c;
    float4 v0 = *(const float4*)wp;
    float4 v1 = *(const float4*)(wp + 4);
    unsigned short* dst = wf + ((long)(blk * 64 + lane)) * 8;
    unsigned int r0 = f2bf(v0.x) | ((unsigned int)f2bf(v0.y) << 16);
    unsigned int r1 = f2bf(v0.z) | ((unsigned int)f2bf(v0.w) << 16);
    unsigned int r2 = f2bf(v1.x) | ((unsigned int)f2bf(v1.y) << 16);
    unsigned int r3 = f2bf(v1.z) | ((unsigned int)f2bf(v1.w) << 16);
    uint4 pk = {r0, r1, r2, r3};
    *(uint4*)dst = pk;
}

// ---------------- MFMA GEMM: y = W @ x (+ GN-fold / + residual + GN-stat partials) ----
// RESID epilogue also accumulates per-group (sum, sumsq) partials of the POST-residual
// values: group = mt*4 + (r>>2) (exact: row = (r&3)+8*(r>>2)+4*hh, so row>>3 == r>>2).
// Per-block partials -> part[(b*32+g)*960 + tile][2]; k_gnred2 reduces over 960 tiles.
#define LDK 264
template <bool GN, bool RESID>
__global__ __launch_bounds__(256) void k_gemm256(float* __restrict__ x,
                                                 const unsigned short* __restrict__ wf,
                                                 const float* __restrict__ stats,
                                                 const float* __restrict__ gn_w,
                                                 const float* __restrict__ gn_b,
                                                 float* __restrict__ part) {
    __shared__ unsigned short xs[64 * LDK];
    __shared__ float scl_s[256], sh_s[256];
    __shared__ float gs[64];
    int tid = threadIdx.x;
    int b = blockIdx.y;
    int pix0 = blockIdx.x * 64;
    float* xb = x + (long)b * 256 * HW2;

    if (RESID && tid < 64) gs[tid] = 0.f;

    if (GN) {
        int c = tid;
        int g = c >> 3;
        float mean = stats[(b * 32 + g) * 2];
        float rstd = stats[(b * 32 + g) * 2 + 1];
        float s = rstd * gn_w[c];
        scl_s[c] = s;
        sh_s[c] = gn_b[c] - mean * s;
        __syncthreads();
    }

#pragma unroll
    for (int it = 0; it < 4; it++) {
        int c0 = ((tid >> 4) << 2) + it * 64;
        int px = (tid & 15) << 2;
        const float* gp = xb + (long)c0 * HW2 + pix0 + px;
        float4 v0 = *(const float4*)gp;
        float4 v1 = *(const float4*)(gp + HW2);
        float4 v2 = *(const float4*)(gp + 2 * HW2);
        float4 v3 = *(const float4*)(gp + 3 * HW2);
        if (GN) {
            float s0 = scl_s[c0], h0 = sh_s[c0];
            float s1 = scl_s[c0 + 1], h1 = sh_s[c0 + 1];
            float s2 = scl_s[c0 + 2], h2 = sh_s[c0 + 2];
            float s3 = scl_s[c0 + 3], h3 = sh_s[c0 + 3];
            v0.x = v0.x * s0 + h0; v0.y = v0.y * s0 + h0; v0.z = v0.z * s0 + h0; v0.w = v0.w * s0 + h0;
            v1.x = v1.x * s1 + h1; v1.y = v1.y * s1 + h1; v1.z = v1.z * s1 + h1; v1.w = v1.w * s1 + h1;
            v2.x = v2.x * s2 + h2; v2.y = v2.y * s2 + h2; v2.z = v2.z * s2 + h2; v2.w = v2.w * s2 + h2;
            v3.x = v3.x * s3 + h3; v3.y = v3.y * s3 + h3; v3.z = v3.z * s3 + h3; v3.w = v3.w * s3 + h3;
        }
        float p0[4] = {v0.x, v0.y, v0.z, v0.w};
        float p1[4] = {v1.x, v1.y, v1.z, v1.w};
        float p2[4] = {v2.x, v2.y, v2.z, v2.w};
        float p3[4] = {v3.x, v3.y, v3.z, v3.w};
#pragma unroll
        for (int p = 0; p < 4; p++) {
            ushort4 u;
            u.x = f2bf(p0[p]); u.y = f2bf(p1[p]); u.z = f2bf(p2[p]); u.w = f2bf(p3[p]);
            *(ushort4*)&xs[(px + p) * LDK + c0] = u;
        }
    }
    __syncthreads();

    int lane = tid & 63, wv = tid >> 6;
    fvec16 acc[2][2];
#pragma unroll
    for (int mi = 0; mi < 2; mi++)
#pragma unroll
        for (int ni = 0; ni < 2; ni++)
            acc[mi][ni] = (fvec16)(0.f);

    int n_in = lane & 31;
    int koff = (lane >> 5) * 8;
#pragma unroll
    for (int ks = 0; ks < 16; ks++) {
        s8b a0 = *(const s8b*)(wf + ((long)(((wv * 2 + 0) * 16 + ks) * 64 + lane)) * 8);
        s8b a1 = *(const s8b*)(wf + ((long)(((wv * 2 + 1) * 16 + ks) * 64 + lane)) * 8);
        s8b b0 = *(const s8b*)&xs[(0 + n_in) * LDK + ks * 16 + koff];
        s8b b1 = *(const s8b*)&xs[(32 + n_in) * LDK + ks * 16 + koff];
        acc[0][0] = __builtin_amdgcn_mfma_f32_32x32x16_bf16(a0, b0, acc[0][0], 0, 0, 0);
        acc[0][1] = __builtin_amdgcn_mfma_f32_32x32x16_bf16(a0, b1, acc[0][1], 0, 0, 0);
        acc[1][0] = __builtin_amdgcn_mfma_f32_32x32x16_bf16(a1, b0, acc[1][0], 0, 0, 0);
        acc[1][1] = __builtin_amdgcn_mfma_f32_32x32x16_bf16(a1, b1, acc[1][1], 0, 0, 0);
    }

    int hh = lane >> 5;
    float ls[2][4], lq[2][4];
    if (RESID) {
#pragma unroll
        for (int mi = 0; mi < 2; mi++)
#pragma unroll
            for (int gq = 0; gq < 4; gq++) { ls[mi][gq] = 0.f; lq[mi][gq] = 0.f; }
    }
#pragma unroll
    for (int mi = 0; mi < 2; mi++) {
        int mt = wv * 2 + mi;
#pragma unroll
        for (int ni = 0; ni < 2; ni++) {
            int pix = pix0 + ni * 32 + n_in;
#pragma unroll
            for (int r = 0; r < 16; r++) {
                int row = (r & 3) + 8 * (r >> 2) + 4 * hh;
                long addr = (long)(mt * 32 + row) * HW2 + pix;
                if (RESID) {
                    float v = xb[addr] + 0.1f * acc[mi][ni][r];
                    xb[addr] = v;
                    ls[mi][r >> 2] += v;
                    lq[mi][r >> 2] += v * v;
                } else {
                    xb[addr] = acc[mi][ni][r];
                }
            }
        }
    }
    if (RESID) {
#pragma unroll
        for (int mi = 0; mi < 2; mi++)
#pragma unroll
            for (int gq = 0; gq < 4; gq++) {
                int g = (wv * 2 + mi) * 4 + gq;
                atomicAdd(&gs[g * 2], ls[mi][gq]);
                atomicAdd(&gs[g * 2 + 1], lq[mi][gq]);
            }
        __syncthreads();
        if (tid < 64) {
            int g = tid >> 1, which = tid & 1;
            part[((long)(b * 32 + g) * 960 + blockIdx.x) * 2 + which] = gs[tid];
        }
    }
}

// ---------------- GroupNorm stats reduce: 960 tile-partials -> mean/rstd ----------------
__global__ void k_gnred2(const float* __restrict__ part, float* __restrict__ stats) {
    int t = threadIdx.x;  // 64 = b*32+g
    const float* p = part + (long)t * 960 * 2;
    double s = 0.0, q = 0.0;
    for (int i = 0; i < 960; i++) {
        s += p[2 * i];
        q += p[2 * i + 1];
    }
    double N = 8.0 * HW2;
    double mean = s / N;
    double var = q / N - mean * mean;
    stats[t * 2] = (float)mean;
    stats[t * 2 + 1] = (float)(1.0 / sqrt(var + 1e-5));
}

extern "C" void kernel_launch(void* const* d_in, const int* in_sizes, int n_in,
                              void* d_out, int out_size, void* d_ws, size_t ws_size,
                              hipStream_t stream) {
    const float* src      = (const float*)d_in[0];
    const float* guidance = (const float*)d_in[1];
    const float* pre_w    = (const float*)d_in[2];
    const float* rp1_w1   = (const float*)d_in[3];
    const float* rp1_b1   = (const float*)d_in[4];
    const float* rp1_w2   = (const float*)d_in[5];
    const float* rp1_b2   = (const float*)d_in[6];
    const float* temp1    = (const float*)d_in[7];
    const float* sigma1   = (const float*)d_in[8];
    const float* rp2_w1   = (const float*)d_in[9];
    const float* rp2_b1   = (const float*)d_in[10];
    const float* rp2_w2   = (const float*)d_in[11];
    const float* rp2_b2   = (const float*)d_in[12];
    const float* temp2    = (const float*)d_in[13];
    const float* sigma2   = (const float*)d_in[14];
    const float* fixup_w  = (const float*)d_in[15];
    const float* gn_w     = (const float*)d_in[16];
    const float* gn_b     = (const float*)d_in[17];
    const float* proj_w   = (const float*)d_in[18];
    float* out = (float*)d_out;

    // ---- workspace arena ----
    char* ws = (char*)d_ws;
    size_t off = 0;
    auto alloc = [&](size_t bytes) { size_t o = off; off = (off + bytes + 255) & ~(size_t)255; return o; };
    float* gdown  = (float*)(ws + alloc((size_t)2 * 3 * 192 * 1280 * 4));
    float* gbuf   = (float*)(ws + alloc((size_t)2 * 3 * 192 * 320 * 4));
    float* projb  = (float*)(ws + alloc((size_t)2 * 32 * 192 * 320 * 4));
    float* x1     = (float*)(ws + alloc((size_t)2 * 256 * 48 * 80 * 4));
    float* out1   = (float*)(ws + alloc((size_t)2 * 256 * 96 * 160 * 4));
    float* ckbuf  = (float*)(ws + alloc((size_t)2 * 49 * 192 * 320 * 4));   // reused across steps
    unsigned short* wfFix  = (unsigned short*)(ws + alloc(65536 * 2));
    unsigned short* wfProj = (unsigned short*)(ws + alloc(65536 * 2));
    float* gpart  = (float*)(ws + alloc((size_t)64 * 960 * 2 * 4));
    float* stats  = (float*)(ws + alloc(64 * 2 * 4));

    // weight prep (bf16 MFMA fragment order)
    k_prepw<<<128, 64, 0, stream>>>(fixup_w, wfFix);
    k_prepw<<<128, 64, 0, stream>>>(proj_w, wfProj);

    // pre-projection 384->256 (2 outputs per block)
    k_preproj<<<256, 256, 0, stream>>>(src, pre_w, x1);

    // ---- JBU step 1: 48x80 -> 96x160 ----
    {
        const int H = 96, W = 160, HW = H * W;
        k_down_h<<<(2 * 3 * H * 1280) / 256, 256, 0, stream>>>(guidance, gdown, H, 8.f);
        k_down_w<<<(2 * 3 * HW + 255) / 256, 256, 0, stream>>>(gdown, gbuf, H, W, 8.f);
        k_proj<<<(2 * HW + 255) / 256, 256, 0, stream>>>(gbuf, projb, rp1_w1, rp1_b1, rp1_w2, rp1_b2, HW);
        k_ck<<<dim3(W / 16, H / 16, 2), 256, 0, stream>>>(projb, ckbuf, temp1, sigma1, H, W);
        k_apply<4><<<dim3(W / 16, H / 16, 2 * 4), 256, 0, stream>>>(x1, ckbuf, out1, H, W, 48, 80);
    }

    // ---- JBU step 2: 96x160 -> 192x320 ----
    {
        const int H = 192, W = 320, HW = H * W;
        k_down_h<<<(2 * 3 * H * 1280) / 256, 256, 0, stream>>>(guidance, gdown, H, 4.f);
        k_down_w<<<(2 * 3 * HW + 255) / 256, 256, 0, stream>>>(gdown, gbuf, H, W, 4.f);
        k_proj<<<(2 * HW + 255) / 256, 256, 0, stream>>>(gbuf, projb, rp2_w1, rp2_b1, rp2_w2, rp2_b2, HW);
        k_ck<<<dim3(W / 16, H / 16, 2), 256, 0, stream>>>(projb, ckbuf, temp2, sigma2, H, W);
        k_apply<4><<<dim3(W / 16, H / 16, 2 * 4), 256, 0, stream>>>(out1, ckbuf, out, H, W, 96, 160);
    }

    // ---- fixup residual (+ fused GN-stat partials): out = out + 0.1 * W @ out ----
    k_gemm256<false, true><<<dim3(960, 2), 256, 0, stream>>>(out, wfFix, nullptr, nullptr, nullptr, gpart);
    // ---- GroupNorm stats reduce ----
    k_gnred2<<<1, 64, 0, stream>>>(gpart, stats);
    // ---- GN affine + final projection (MFMA, in-place) ----
    k_gemm256<true, false><<<dim3(960, 2), 256, 0, stream>>>(out, wfProj, stats, gn_w, gn_b, nullptr);
}

// Round 9
// 892.592 us; speedup vs baseline: 1.6464x; 1.0812x over previous
//
#include <hip/hip_runtime.h>
#include <math.h>

#define B_ 2
#define C_ 256
#define FD_ 384
#define K_ 32
#define HW2 61440   // 192*320

typedef __attribute__((ext_vector_type(8))) short s8b;      // 8 bf16 (4 VGPRs)
typedef __attribute__((ext_vector_type(16))) float fvec16;  // MFMA 32x32 accumulator
typedef __attribute__((ext_vector_type(4))) float f4;       // LDS b128 unit

__device__ __forceinline__ unsigned short f2bf(float f) {
    unsigned int u = __builtin_bit_cast(unsigned int, f);
    u = (u + 0x7fffu + ((u >> 16) & 1u)) >> 16;
    return (unsigned short)u;
}

// ---------------- pre_proj: conv1x1 384->256 over 48x80 (2 outputs/block) ----------------
__global__ void k_preproj(const float* __restrict__ src, const float* __restrict__ w,
                          float* __restrict__ out) {
    __shared__ float w_s[2 * FD_];
    int bo = blockIdx.x;            // 256 blocks
    int b = bo >> 7, o = (bo & 127) * 2;
    int tid = threadIdx.x;
    for (int i = tid; i < 2 * FD_; i += 256) w_s[i] = w[o * FD_ + i];   // rows o, o+1 contiguous
    __syncthreads();
    float a0[15], a1[15];
#pragma unroll
    for (int k = 0; k < 15; k++) { a0[k] = 0.f; a1[k] = 0.f; }
    const float* sp = src + (long)b * FD_ * 3840;
    for (int c = 0; c < FD_; c++) {
        float wv0 = w_s[c];
        float wv1 = w_s[FD_ + c];
        const float* row = sp + (long)c * 3840;
#pragma unroll
        for (int k = 0; k < 15; k++) {
            float r = row[tid + k * 256];
            a0[k] += wv0 * r;
            a1[k] += wv1 * r;
        }
    }
    float* op = out + ((long)b * 256 + o) * 3840;
#pragma unroll
    for (int k = 0; k < 15; k++) op[tid + k * 256] = a0[k];
#pragma unroll
    for (int k = 0; k < 15; k++) op[3840 + tid + k * 256] = a1[k];
}

// ---------------- guidance downsample (tent, antialias) ----------------
__global__ void k_down_h(const float* __restrict__ in, float* __restrict__ out, int Ho, float s) {
    long idx = (long)blockIdx.x * 256 + threadIdx.x;
    long total = (long)B_ * 3 * Ho * 1280;
    if (idx >= total) return;
    int x = (int)(idx % 1280);
    long t1 = idx / 1280;
    int i = (int)(t1 % Ho);
    long t2 = t1 / Ho;
    int c = (int)(t2 % 3);
    int b = (int)(t2 / 3);
    float sf = (i + 0.5f) * s - 0.5f;
    int j0 = (int)floorf(sf - s) + 1;
    int j1 = (int)ceilf(sf + s) - 1;
    float acc = 0.f, wsum = 0.f;
    const float* ip = in + ((long)(b * 3 + c) * 768) * 1280 + x;
    for (int j = j0; j <= j1; j++) {
        if (j < 0 || j >= 768) continue;
        float wv = 1.f - fabsf((float)j - sf) / s;
        acc += wv * ip[(long)j * 1280];
        wsum += wv;
    }
    out[idx] = acc / wsum;
}

__global__ void k_down_w(const float* __restrict__ in, float* __restrict__ out, int Ho, int Wo, float s) {
    long idx = (long)blockIdx.x * 256 + threadIdx.x;
    long total = (long)B_ * 3 * Ho * Wo;
    if (idx >= total) return;
    int i = (int)(idx % Wo);
    long t1 = idx / Wo;
    int y = (int)(t1 % Ho);
    long t2 = t1 / Ho;
    int c = (int)(t2 % 3);
    int b = (int)(t2 / 3);
    float sf = (i + 0.5f) * s - 0.5f;
    int j0 = (int)floorf(sf - s) + 1;
    int j1 = (int)ceilf(sf + s) - 1;
    float acc = 0.f, wsum = 0.f;
    const float* ip = in + ((long)(b * 3 + c) * Ho + y) * 1280;
    for (int j = j0; j <= j1; j++) {
        if (j < 0 || j >= 1280) continue;
        float wv = 1.f - fabsf((float)j - sf) / s;
        acc += wv * ip[j];
        wsum += wv;
    }
    out[idx] = acc / wsum;
}

// ---------------- range projection MLP ----------------
__global__ void k_proj(const float* __restrict__ g, float* __restrict__ proj,
                       const float* __restrict__ w1, const float* __restrict__ b1,
                       const float* __restrict__ w2, const float* __restrict__ b2,
                       int HW) {
    __shared__ float w1_s[96], b1_s[32], w2_s[1024], b2_s[32];
    int tid = threadIdx.x;
    if (tid < 96) w1_s[tid] = w1[tid];
    if (tid < 32) { b1_s[tid] = b1[tid]; b2_s[tid] = b2[tid]; }
    for (int i = tid; i < 1024; i += 256) w2_s[i] = w2[i];
    __syncthreads();
    long idx = (long)blockIdx.x * 256 + tid;
    if (idx >= (long)B_ * HW) return;
    int b = (int)(idx / HW);
    int pix = (int)(idx % HW);
    const float* gp = g + (long)b * 3 * HW + pix;
    float g0 = gp[0], g1 = gp[HW], g2 = gp[2 * (long)HW];
    float hg[32];
#pragma unroll
    for (int k = 0; k < 32; k++) {
        float h = b1_s[k] + w1_s[k * 3] * g0 + w1_s[k * 3 + 1] * g1 + w1_s[k * 3 + 2] * g2;
        hg[k] = 0.5f * h * (1.f + erff(h * 0.70710678118654752f));
    }
    float* pp = proj + (long)b * 32 * HW + pix;
#pragma unroll
    for (int j = 0; j < 32; j++) {
        float a = b2_s[j];
#pragma unroll
        for (int k = 0; k < 32; k++) a += w2_s[j * 32 + k] * hg[k];
        pp[(long)j * HW] = a;
    }
}

// ======== k_ck: sims + softmax + spatial + renorm -> ck buffer [b][49][H][W] ========
__global__ __launch_bounds__(256) void k_ck(const float* __restrict__ proj,
                                            float* __restrict__ ckb,
                                            const float* __restrict__ temp,
                                            const float* __restrict__ sigma,
                                            int H, int W) {
    __shared__ __align__(16) float smem[9680];   // halo [484][20]

    int tid = threadIdx.x;
    int tx = tid & 15, ty = tid >> 4;
    int x0 = blockIdx.x * 16, y0 = blockIdx.y * 16;
    int b = blockIdx.z;

    float ck[49];
#pragma unroll
    for (int p = 0; p < 49; p++) ck[p] = 0.f;

    const float* pb = proj + (long)b * 32 * H * W;
    const f4* hs4 = (const f4*)smem;
#pragma unroll 1
    for (int pass = 0; pass < 2; pass++) {
        int k0 = pass * 16;
        for (int i = tid; i < 16 * 484; i += 256) {
            int k = i / 484;
            int rem = i - k * 484;
            int yy = rem / 22, xx = rem - yy * 22;
            int y = y0 - 3 + yy; y = y < 0 ? -y : (y >= H ? 2 * H - 2 - y : y);
            int x = x0 - 3 + xx; x = x < 0 ? -x : (x >= W ? 2 * W - 2 - x : x);
            smem[rem * 20 + k] = pb[((long)(k0 + k) * H + y) * W + x];
        }
        __syncthreads();
        int pc = ((ty + 3) * 22 + (tx + 3)) * 5;
        f4 c0 = hs4[pc + 0], c1 = hs4[pc + 1], c2 = hs4[pc + 2], c3 = hs4[pc + 3];
#pragma unroll
        for (int dy = 0; dy < 7; dy++) {
#pragma unroll
            for (int dx = 0; dx < 7; dx++) {
                int pn = ((ty + dy) * 22 + (tx + dx)) * 5;
                f4 s = hs4[pn + 0] * c0;
                s += hs4[pn + 1] * c1;
                s += hs4[pn + 2] * c2;
                s += hs4[pn + 3] * c3;
                ck[dy * 7 + dx] += (s.x + s.y) + (s.z + s.w);
            }
        }
        __syncthreads();
    }

    // softmax * spatial, renormalize (registers only)
    {
        float t = expf(temp[0]);
        t = fminf(fmaxf(t, 1e-4f), 1e4f);
        float m = -1e30f;
#pragma unroll
        for (int p = 0; p < 49; p++) { ck[p] *= t; m = fmaxf(m, ck[p]); }
        float ssum = 0.f;
#pragma unroll
        for (int p = 0; p < 49; p++) { ck[p] = expf(ck[p] - m); ssum += ck[p]; }
        float inv = 1.f / ssum;
        float sg = sigma[0];
        float dc = 1.f / (2.f * sg * sg);
        float csum = 0.f;
#pragma unroll
        for (int p = 0; p < 49; p++) {
            int dy = p / 7, dx = p % 7;
            float d0 = (dy - 3) / 3.f, d1 = (dx - 3) / 3.f;
            float sp = expf(-(d0 * d0 + d1 * d1) * dc);
            ck[p] = ck[p] * inv * sp;
            csum += ck[p];
        }
        float r = 1.f / fmaxf(csum, 1e-7f);
#pragma unroll
        for (int p = 0; p < 49; p++) ck[p] *= r;
    }

    // write out: [b][p][y][x], coalesced over tx
    long HWl = (long)H * W;
    float* cp = ckb + (long)b * 49 * HWl + (long)(y0 + ty) * W + (x0 + tx);
#pragma unroll
    for (int p = 0; p < 49; p++) cp[(long)p * HWl] = ck[p];
}

// ======== k_apply: bicubic-in-LDS + 49-tap apply (ck STREAMED from global) ========
// ck streamed 7-at-a-time per chunk (no cross-loop 49-reg live set).
// PLAIN __launch_bounds__(256) — DO NOT add a min-waves arg: every cap tried
// collapsed the allocator to 64-84 VGPR + wholesale ck scratch spill (2-6x slower).
// All stride/offset arithmetic is 32-bit (max offset 12 MB): VGPR bucketing is
// 64/128/256 (m69) and the 132-VGPR version paid the 256 bucket (2 waves/SIMD);
// int addressing aims <=128 -> 4 waves/SIMD. LDS = 35808 B.
template <int CS>
__global__ __launch_bounds__(256) void k_apply(const float* __restrict__ lo,
                                               const float* ckb,
                                               float* out,
                                               int H, int W, int h, int w) {
    __shared__ __align__(16) float smem[8952];

    int tid = threadIdx.x;
    int tx = tid & 15, ty = tid >> 4;
    int x0 = blockIdx.x * 16, y0 = blockIdx.y * 16;
    int b = blockIdx.z / CS;
    int c_base = (blockIdx.z % CS) * (256 / CS);

    int HW = H * W;          // <= 61440, all p*HW offsets fit int
    const float* cp = ckb + (long)b * 49 * HW + (y0 + ty) * W + (x0 + tx);

    // ---- contiguous 22-window covering all reflect-padded taps ----
    int ws_y = y0 - 3; if (ws_y < 0) ws_y = 0; if (ws_y > H - 22) ws_y = H - 22;
    int ws_x = x0 - 3; if (ws_x < 0) ws_x = 0; if (ws_x > W - 22) ws_x = W - 22;
    int ls_y = (ws_y >> 1) - 2, ls_x = (ws_x >> 1) - 2;
    int ry[7], rx[7];   // pre-scaled LDS offsets: row*45, col*2
#pragma unroll
    for (int d = 0; d < 7; d++) {
        int v = y0 + ty + d - 3; v = v < 0 ? -v : (v >= H ? 2 * H - 2 - v : v);
        ry[d] = (v - ws_y) * 45;
        int u = x0 + tx + d - 3; u = u < 0 ? -u : (u >= W ? 2 * W - 2 - u : u);
        rx[d] = (u - ws_x) * 2;
    }

    // staging coords for lo tile (per-element clamp handles bicubic edge-clamp)
    int lrow = ls_y + ty; lrow = lrow < 0 ? 0 : (lrow >= h ? h - 1 : lrow);
    int lcol = ls_x + tx; lcol = lcol < 0 ? 0 : (lcol >= w ? w - 1 : lcol);

    // f4 tiles (channel-packed, 4 ch per f4, 2 groups = 8 ch per chunk)
    f4* lo4  = (f4*)smem;                  // [16 rows][33 f4]
    f4* tmp4 = (f4*)(smem + 2112);         // [16 rows][45 f4]
    f4* hr4  = (f4*)(smem + 2112 + 2880);  // [22 rows][45 f4]

    int hw = h * w;          // <= 15360, int strides

    const int nchunk = (256 / CS) / 8;
#pragma unroll 1
    for (int cc = 0; cc < nchunk; cc++) {
        int c0 = c_base + cc * 8;
        // stage lo: gather 8 channels, two 4-channel halves (limits transient f4 liveness)
        const float* lp = lo + ((long)(b * 256 + c0) * h + lrow) * w + lcol;
        {
            f4 va;
            va.x = lp[0];      va.y = lp[hw];     va.z = lp[2 * hw]; va.w = lp[3 * hw];
            lo4[ty * 33 + tx * 2 + 0] = va;
        }
        {
            f4 vb;
            vb.x = lp[4 * hw]; vb.y = lp[5 * hw]; vb.z = lp[6 * hw]; vb.w = lp[7 * hw];
            lo4[ty * 33 + tx * 2 + 1] = vb;
        }
        __syncthreads();

        // horizontal bicubic: tmp [16 lo-rows][22 hr-cols][2 g]  (704 f4)
#pragma unroll
        for (int it = 0; it < 3; it++) {
            int e = tid + it * 256;
            if (e < 704) {
                int g = e & 1, rem = e >> 1;
                int j = rem / 22, Xp = rem - j * 22;
                int X = ws_x + Xp;
                int ix = (X >> 1) - ls_x;
                const f4* lr = lo4 + j * 33 + g;
                f4 v;
                if (X & 1)
                    v = -0.10546875f * lr[(ix - 1) * 2] + 0.87890625f * lr[ix * 2] + 0.26171875f * lr[(ix + 1) * 2] - 0.03515625f * lr[(ix + 2) * 2];
                else
                    v = -0.03515625f * lr[(ix - 2) * 2] + 0.26171875f * lr[(ix - 1) * 2] + 0.87890625f * lr[ix * 2] - 0.10546875f * lr[(ix + 1) * 2];
                tmp4[j * 45 + Xp * 2 + g] = v;
            }
        }
        __syncthreads();

        // vertical bicubic: hr [22 rows][22 cols][2 g]  (968 f4)
#pragma unroll
        for (int it = 0; it < 4; it++) {
            int e = tid + it * 256;
            if (e < 968) {
                int g = e & 1, rem = e >> 1;
                int i = rem / 22, Xp = rem - i * 22;
                int Y = ws_y + i;
                int jy = (Y >> 1) - ls_y;
                const f4* tc = tmp4 + Xp * 2 + g;
                f4 v;
                if (Y & 1)
                    v = -0.10546875f * tc[(jy - 1) * 45] + 0.87890625f * tc[jy * 45] + 0.26171875f * tc[(jy + 1) * 45] - 0.03515625f * tc[(jy + 2) * 45];
                else
                    v = -0.03515625f * tc[(jy - 2) * 45] + 0.26171875f * tc[(jy - 1) * 45] + 0.87890625f * tc[jy * 45] - 0.10546875f * tc[(jy + 1) * 45];
                hr4[i * 45 + Xp * 2 + g] = v;
            }
        }
        __syncthreads();

        // apply 49 taps, both channel-groups per tap-row; ck streamed 7-at-a-time
        f4 acc0 = (f4)(0.f), acc1 = (f4)(0.f);
#pragma unroll
        for (int dy = 0; dy < 7; dy++) {
            float c_[7];
            int cko = dy * 7 * HW;
#pragma unroll
            for (int dx = 0; dx < 7; dx++) c_[dx] = cp[cko + dx * HW];
            const f4* hrow = hr4 + ry[dy];
#pragma unroll
            for (int dx = 0; dx < 7; dx++) {
                acc0 += c_[dx] * hrow[rx[dx]];
                acc1 += c_[dx] * hrow[rx[dx] + 1];
            }
        }
        float* op = out + ((long)(b * 256 + c0) * H + (y0 + ty)) * W + (x0 + tx);
        op[0]          = acc0.x;
        op[HW]         = acc0.y;
        op[2 * HW]     = acc0.z;
        op[3 * HW]     = acc0.w;
        op[4 * HW]     = acc1.x;
        op[5 * HW]     = acc1.y;
        op[6 * HW]     = acc1.z;
        op[7 * HW]     = acc1.w;
        // no trailing barrier: next chunk's stage-sync orders apply reads vs later writes
    }
}

// ---------------- prep: pack W[o][c] fp32 -> bf16 MFMA A-fragment order ----------------
__global__ void k_prepw(const float* __restrict__ w, unsigned short* __restrict__ wf) {
    int blk = blockIdx.x;           // mt*16+ks, 128 blocks
    int lane = threadIdx.x;         // 64
    int mt = blk >> 4, ks = blk & 15;
    int o = mt * 32 + (lane & 31);
    int c = ks * 16 + (lane >> 5) * 8;
    const float* wp = w + (long)o * 256 + c;
    float4 v0 = *(const float4*)wp;
    float4 v1 = *(const float4*)(wp + 4);
    unsigned short* dst = wf + ((long)(blk * 64 + lane)) * 8;
    unsigned int r0 = f2bf(v0.x) | ((unsigned int)f2bf(v0.y) << 16);
    unsigned int r1 = f2bf(v0.z) | ((unsigned int)f2bf(v0.w) << 16);
    unsigned int r2 = f2bf(v1.x) | ((unsigned int)f2bf(v1.y) << 16);
    unsigned int r3 = f2bf(v1.z) | ((unsigned int)f2bf(v1.w) << 16);
    uint4 pk = {r0, r1, r2, r3};
    *(uint4*)dst = pk;
}

// ---------------- MFMA GEMM: y = W @ x (+ GN-fold / + residual + GN-stat partials) ----
#define LDK 264
template <bool GN, bool RESID>
__global__ __launch_bounds__(256) void k_gemm256(float* __restrict__ x,
                                                 const unsigned short* __restrict__ wf,
                                                 const float* __restrict__ stats,
                                                 const float* __restrict__ gn_w,
                                                 const float* __restrict__ gn_b,
                                                 float* __restrict__ part) {
    __shared__ unsigned short xs[64 * LDK];
    __shared__ float scl_s[256], sh_s[256];
    __shared__ float gs[64];
    int tid = threadIdx.x;
    int b = blockIdx.y;
    int pix0 = blockIdx.x * 64;
    float* xb = x + (long)b * 256 * HW2;

    if (RESID && tid < 64) gs[tid] = 0.f;

    if (GN) {
        int c = tid;
        int g = c >> 3;
        float mean = stats[(b * 32 + g) * 2];
        float rstd = stats[(b * 32 + g) * 2 + 1];
        float s = rstd * gn_w[c];
        scl_s[c] = s;
        sh_s[c] = gn_b[c] - mean * s;
        __syncthreads();
    }

#pragma unroll
    for (int it = 0; it < 4; it++) {
        int c0 = ((tid >> 4) << 2) + it * 64;
        int px = (tid & 15) << 2;
        const float* gp = xb + (long)c0 * HW2 + pix0 + px;
        float4 v0 = *(const float4*)gp;
        float4 v1 = *(const float4*)(gp + HW2);
        float4 v2 = *(const float4*)(gp + 2 * HW2);
        float4 v3 = *(const float4*)(gp + 3 * HW2);
        if (GN) {
            float s0 = scl_s[c0], h0 = sh_s[c0];
            float s1 = scl_s[c0 + 1], h1 = sh_s[c0 + 1];
            float s2 = scl_s[c0 + 2], h2 = sh_s[c0 + 2];
            float s3 = scl_s[c0 + 3], h3 = sh_s[c0 + 3];
            v0.x = v0.x * s0 + h0; v0.y = v0.y * s0 + h0; v0.z = v0.z * s0 + h0; v0.w = v0.w * s0 + h0;
            v1.x = v1.x * s1 + h1; v1.y = v1.y * s1 + h1; v1.z = v1.z * s1 + h1; v1.w = v1.w * s1 + h1;
            v2.x = v2.x * s2 + h2; v2.y = v2.y * s2 + h2; v2.z = v2.z * s2 + h2; v2.w = v2.w * s2 + h2;
            v3.x = v3.x * s3 + h3; v3.y = v3.y * s3 + h3; v3.z = v3.z * s3 + h3; v3.w = v3.w * s3 + h3;
        }
        float p0[4] = {v0.x, v0.y, v0.z, v0.w};
        float p1[4] = {v1.x, v1.y, v1.z, v1.w};
        float p2[4] = {v2.x, v2.y, v2.z, v2.w};
        float p3[4] = {v3.x, v3.y, v3.z, v3.w};
#pragma unroll
        for (int p = 0; p < 4; p++) {
            ushort4 u;
            u.x = f2bf(p0[p]); u.y = f2bf(p1[p]); u.z = f2bf(p2[p]); u.w = f2bf(p3[p]);
            *(ushort4*)&xs[(px + p) * LDK + c0] = u;
        }
    }
    __syncthreads();

    int lane = tid & 63, wv = tid >> 6;
    fvec16 acc[2][2];
#pragma unroll
    for (int mi = 0; mi < 2; mi++)
#pragma unroll
        for (int ni = 0; ni < 2; ni++)
            acc[mi][ni] = (fvec16)(0.f);

    int n_in = lane & 31;
    int koff = (lane >> 5) * 8;
#pragma unroll
    for (int ks = 0; ks < 16; ks++) {
        s8b a0 = *(const s8b*)(wf + ((long)(((wv * 2 + 0) * 16 + ks) * 64 + lane)) * 8);
        s8b a1 = *(const s8b*)(wf + ((long)(((wv * 2 + 1) * 16 + ks) * 64 + lane)) * 8);
        s8b b0 = *(const s8b*)&xs[(0 + n_in) * LDK + ks * 16 + koff];
        s8b b1 = *(const s8b*)&xs[(32 + n_in) * LDK + ks * 16 + koff];
        acc[0][0] = __builtin_amdgcn_mfma_f32_32x32x16_bf16(a0, b0, acc[0][0], 0, 0, 0);
        acc[0][1] = __builtin_amdgcn_mfma_f32_32x32x16_bf16(a0, b1, acc[0][1], 0, 0, 0);
        acc[1][0] = __builtin_amdgcn_mfma_f32_32x32x16_bf16(a1, b0, acc[1][0], 0, 0, 0);
        acc[1][1] = __builtin_amdgcn_mfma_f32_32x32x16_bf16(a1, b1, acc[1][1], 0, 0, 0);
    }

    int hh = lane >> 5;
    float ls[2][4], lq[2][4];
    if (RESID) {
#pragma unroll
        for (int mi = 0; mi < 2; mi++)
#pragma unroll
            for (int gq = 0; gq < 4; gq++) { ls[mi][gq] = 0.f; lq[mi][gq] = 0.f; }
    }
#pragma unroll
    for (int mi = 0; mi < 2; mi++) {
        int mt = wv * 2 + mi;
#pragma unroll
        for (int ni = 0; ni < 2; ni++) {
            int pix = pix0 + ni * 32 + n_in;
#pragma unroll
            for (int r = 0; r < 16; r++) {
                int row = (r & 3) + 8 * (r >> 2) + 4 * hh;
                long addr = (long)(mt * 32 + row) * HW2 + pix;
                if (RESID) {
                    float v = xb[addr] + 0.1f * acc[mi][ni][r];
                    xb[addr] = v;
                    ls[mi][r >> 2] += v;
                    lq[mi][r >> 2] += v * v;
                } else {
                    xb[addr] = acc[mi][ni][r];
                }
            }
        }
    }
    if (RESID) {
#pragma unroll
        for (int mi = 0; mi < 2; mi++)
#pragma unroll
            for (int gq = 0; gq < 4; gq++) {
                int g = (wv * 2 + mi) * 4 + gq;
                atomicAdd(&gs[g * 2], ls[mi][gq]);
                atomicAdd(&gs[g * 2 + 1], lq[mi][gq]);
            }
        __syncthreads();
        if (tid < 64) {
            int g = tid >> 1, which = tid & 1;
            part[((long)(b * 32 + g) * 960 + blockIdx.x) * 2 + which] = gs[tid];
        }
    }
}

// ---------------- GroupNorm stats reduce: 960 tile-partials -> mean/rstd ----------------
// 64 blocks (one per b*32+g) x 256 threads; LDS tree reduce. The previous 1-block/64-thread
// serial version was a single-wave latency tail (~50-100us).
__global__ void k_gnred2(const float* __restrict__ part, float* __restrict__ stats) {
    __shared__ double s_s[256], q_s[256];
    int t = blockIdx.x;   // b*32+g
    const float* p = part + (long)t * 960 * 2;
    double s = 0.0, q = 0.0;
    for (int i = threadIdx.x; i < 960; i += 256) {
        s += p[2 * i];
        q += p[2 * i + 1];
    }
    s_s[threadIdx.x] = s; q_s[threadIdx.x] = q;
    __syncthreads();
    for (int st = 128; st > 0; st >>= 1) {
        if (threadIdx.x < st) { s_s[threadIdx.x] += s_s[threadIdx.x + st]; q_s[threadIdx.x] += q_s[threadIdx.x + st]; }
        __syncthreads();
    }
    if (threadIdx.x == 0) {
        double N = 8.0 * HW2;
        double mean = s_s[0] / N;
        double var = q_s[0] / N - mean * mean;
        stats[t * 2] = (float)mean;
        stats[t * 2 + 1] = (float)(1.0 / sqrt(var + 1e-5));
    }
}

extern "C" void kernel_launch(void* const* d_in, const int* in_sizes, int n_in,
                              void* d_out, int out_size, void* d_ws, size_t ws_size,
                              hipStream_t stream) {
    const float* src      = (const float*)d_in[0];
    const float* guidance = (const float*)d_in[1];
    const float* pre_w    = (const float*)d_in[2];
    const float* rp1_w1   = (const float*)d_in[3];
    const float* rp1_b1   = (const float*)d_in[4];
    const float* rp1_w2   = (const float*)d_in[5];
    const float* rp1_b2   = (const float*)d_in[6];
    const float* temp1    = (const float*)d_in[7];
    const float* sigma1   = (const float*)d_in[8];
    const float* rp2_w1   = (const float*)d_in[9];
    const float* rp2_b1   = (const float*)d_in[10];
    const float* rp2_w2   = (const float*)d_in[11];
    const float* rp2_b2   = (const float*)d_in[12];
    const float* temp2    = (const float*)d_in[13];
    const float* sigma2   = (const float*)d_in[14];
    const float* fixup_w  = (const float*)d_in[15];
    const float* gn_w     = (const float*)d_in[16];
    const float* gn_b     = (const float*)d_in[17];
    const float* proj_w   = (const float*)d_in[18];
    float* out = (float*)d_out;

    // ---- workspace arena ----
    char* ws = (char*)d_ws;
    size_t off = 0;
    auto alloc = [&](size_t bytes) { size_t o = off; off = (off + bytes + 255) & ~(size_t)255; return o; };
    float* gdown  = (float*)(ws + alloc((size_t)2 * 3 * 192 * 1280 * 4));
    float* gbuf   = (float*)(ws + alloc((size_t)2 * 3 * 192 * 320 * 4));
    float* projb  = (float*)(ws + alloc((size_t)2 * 32 * 192 * 320 * 4));
    float* x1     = (float*)(ws + alloc((size_t)2 * 256 * 48 * 80 * 4));
    float* out1   = (float*)(ws + alloc((size_t)2 * 256 * 96 * 160 * 4));
    float* ckbuf  = (float*)(ws + alloc((size_t)2 * 49 * 192 * 320 * 4));   // reused across steps
    unsigned short* wfFix  = (unsigned short*)(ws + alloc(65536 * 2));
    unsigned short* wfProj = (unsigned short*)(ws + alloc(65536 * 2));
    float* gpart  = (float*)(ws + alloc((size_t)64 * 960 * 2 * 4));
    float* stats  = (float*)(ws + alloc(64 * 2 * 4));

    // weight prep (bf16 MFMA fragment order)
    k_prepw<<<128, 64, 0, stream>>>(fixup_w, wfFix);
    k_prepw<<<128, 64, 0, stream>>>(proj_w, wfProj);

    // pre-projection 384->256 (2 outputs per block)
    k_preproj<<<256, 256, 0, stream>>>(src, pre_w, x1);

    // ---- JBU step 1: 48x80 -> 96x160 ----
    {
        const int H = 96, W = 160, HW = H * W;
        k_down_h<<<(2 * 3 * H * 1280) / 256, 256, 0, stream>>>(guidance, gdown, H, 8.f);
        k_down_w<<<(2 * 3 * HW + 255) / 256, 256, 0, stream>>>(gdown, gbuf, H, W, 8.f);
        k_proj<<<(2 * HW + 255) / 256, 256, 0, stream>>>(gbuf, projb, rp1_w1, rp1_b1, rp1_w2, rp1_b2, HW);
        k_ck<<<dim3(W / 16, H / 16, 2), 256, 0, stream>>>(projb, ckbuf, temp1, sigma1, H, W);
        k_apply<4><<<dim3(W / 16, H / 16, 2 * 4), 256, 0, stream>>>(x1, ckbuf, out1, H, W, 48, 80);
    }

    // ---- JBU step 2: 96x160 -> 192x320 ----
    {
        const int H = 192, W = 320, HW = H * W;
        k_down_h<<<(2 * 3 * H * 1280) / 256, 256, 0, stream>>>(guidance, gdown, H, 4.f);
        k_down_w<<<(2 * 3 * HW + 255) / 256, 256, 0, stream>>>(gdown, gbuf, H, W, 4.f);
        k_proj<<<(2 * HW + 255) / 256, 256, 0, stream>>>(gbuf, projb, rp2_w1, rp2_b1, rp2_w2, rp2_b2, HW);
        k_ck<<<dim3(W / 16, H / 16, 2), 256, 0, stream>>>(projb, ckbuf, temp2, sigma2, H, W);
        k_apply<4><<<dim3(W / 16, H / 16, 2 * 4), 256, 0, stream>>>(out1, ckbuf, out, H, W, 96, 160);
    }

    // ---- fixup residual (+ fused GN-stat partials): out = out + 0.1 * W @ out ----
    k_gemm256<false, true><<<dim3(960, 2), 256, 0, stream>>>(out, wfFix, nullptr, nullptr, nullptr, gpart);
    // ---- GroupNorm stats reduce (parallel) ----
    k_gnred2<<<64, 256, 0, stream>>>(gpart, stats);
    // ---- GN affine + final projection (MFMA, in-place) ----
    k_gemm256<true, false><<<dim3(960, 2), 256, 0, stream>>>(out, wfProj, stats, gn_w, gn_b, nullptr);
}

// Round 10
// 865.093 us; speedup vs baseline: 1.6987x; 1.0318x over previous
//
#include <hip/hip_runtime.h>
#include <math.h>

#define B_ 2
#define C_ 256
#define FD_ 384
#define K_ 32
#define HW2 61440   // 192*320

typedef __attribute__((ext_vector_type(8))) short s8b;      // 8 bf16 (4 VGPRs)
typedef __attribute__((ext_vector_type(16))) float fvec16;  // MFMA 32x32 accumulator
typedef __attribute__((ext_vector_type(4))) float f4;       // LDS b128 unit

__device__ __forceinline__ unsigned short f2bf(float f) {
    unsigned int u = __builtin_bit_cast(unsigned int, f);
    u = (u + 0x7fffu + ((u >> 16) & 1u)) >> 16;
    return (unsigned short)u;
}

// ---------------- pre_proj: conv1x1 384->256 over 48x80 (2 outputs/block) ----------------
__global__ void k_preproj(const float* __restrict__ src, const float* __restrict__ w,
                          float* __restrict__ out) {
    __shared__ float w_s[2 * FD_];
    int bo = blockIdx.x;            // 256 blocks
    int b = bo >> 7, o = (bo & 127) * 2;
    int tid = threadIdx.x;
    for (int i = tid; i < 2 * FD_; i += 256) w_s[i] = w[o * FD_ + i];   // rows o, o+1 contiguous
    __syncthreads();
    float a0[15], a1[15];
#pragma unroll
    for (int k = 0; k < 15; k++) { a0[k] = 0.f; a1[k] = 0.f; }
    const float* sp = src + (long)b * FD_ * 3840;
    for (int c = 0; c < FD_; c++) {
        float wv0 = w_s[c];
        float wv1 = w_s[FD_ + c];
        const float* row = sp + (long)c * 3840;
#pragma unroll
        for (int k = 0; k < 15; k++) {
            float r = row[tid + k * 256];
            a0[k] += wv0 * r;
            a1[k] += wv1 * r;
        }
    }
    float* op = out + ((long)b * 256 + o) * 3840;
#pragma unroll
    for (int k = 0; k < 15; k++) op[tid + k * 256] = a0[k];
#pragma unroll
    for (int k = 0; k < 15; k++) op[3840 + tid + k * 256] = a1[k];
}

// ---------------- guidance downsample (tent, antialias) ----------------
__global__ void k_down_h(const float* __restrict__ in, float* __restrict__ out, int Ho, float s) {
    long idx = (long)blockIdx.x * 256 + threadIdx.x;
    long total = (long)B_ * 3 * Ho * 1280;
    if (idx >= total) return;
    int x = (int)(idx % 1280);
    long t1 = idx / 1280;
    int i = (int)(t1 % Ho);
    long t2 = t1 / Ho;
    int c = (int)(t2 % 3);
    int b = (int)(t2 / 3);
    float sf = (i + 0.5f) * s - 0.5f;
    int j0 = (int)floorf(sf - s) + 1;
    int j1 = (int)ceilf(sf + s) - 1;
    float acc = 0.f, wsum = 0.f;
    const float* ip = in + ((long)(b * 3 + c) * 768) * 1280 + x;
    for (int j = j0; j <= j1; j++) {
        if (j < 0 || j >= 768) continue;
        float wv = 1.f - fabsf((float)j - sf) / s;
        acc += wv * ip[(long)j * 1280];
        wsum += wv;
    }
    out[idx] = acc / wsum;
}

__global__ void k_down_w(const float* __restrict__ in, float* __restrict__ out, int Ho, int Wo, float s) {
    long idx = (long)blockIdx.x * 256 + threadIdx.x;
    long total = (long)B_ * 3 * Ho * Wo;
    if (idx >= total) return;
    int i = (int)(idx % Wo);
    long t1 = idx / Wo;
    int y = (int)(t1 % Ho);
    long t2 = t1 / Ho;
    int c = (int)(t2 % 3);
    int b = (int)(t2 / 3);
    float sf = (i + 0.5f) * s - 0.5f;
    int j0 = (int)floorf(sf - s) + 1;
    int j1 = (int)ceilf(sf + s) - 1;
    float acc = 0.f, wsum = 0.f;
    const float* ip = in + ((long)(b * 3 + c) * Ho + y) * 1280;
    for (int j = j0; j <= j1; j++) {
        if (j < 0 || j >= 1280) continue;
        float wv = 1.f - fabsf((float)j - sf) / s;
        acc += wv * ip[j];
        wsum += wv;
    }
    out[idx] = acc / wsum;
}

// ---------------- range projection MLP ----------------
__global__ void k_proj(const float* __restrict__ g, float* __restrict__ proj,
                       const float* __restrict__ w1, const float* __restrict__ b1,
                       const float* __restrict__ w2, const float* __restrict__ b2,
                       int HW) {
    __shared__ float w1_s[96], b1_s[32], w2_s[1024], b2_s[32];
    int tid = threadIdx.x;
    if (tid < 96) w1_s[tid] = w1[tid];
    if (tid < 32) { b1_s[tid] = b1[tid]; b2_s[tid] = b2[tid]; }
    for (int i = tid; i < 1024; i += 256) w2_s[i] = w2[i];
    __syncthreads();
    long idx = (long)blockIdx.x * 256 + tid;
    if (idx >= (long)B_ * HW) return;
    int b = (int)(idx / HW);
    int pix = (int)(idx % HW);
    const float* gp = g + (long)b * 3 * HW + pix;
    float g0 = gp[0], g1 = gp[HW], g2 = gp[2 * (long)HW];
    float hg[32];
#pragma unroll
    for (int k = 0; k < 32; k++) {
        float h = b1_s[k] + w1_s[k * 3] * g0 + w1_s[k * 3 + 1] * g1 + w1_s[k * 3 + 2] * g2;
        hg[k] = 0.5f * h * (1.f + erff(h * 0.70710678118654752f));
    }
    float* pp = proj + (long)b * 32 * HW + pix;
#pragma unroll
    for (int j = 0; j < 32; j++) {
        float a = b2_s[j];
#pragma unroll
        for (int k = 0; k < 32; k++) a += w2_s[j * 32 + k] * hg[k];
        pp[(long)j * HW] = a;
    }
}

// ======== k_ck: sims + softmax + spatial + renorm -> ck buffer [b][49][H][W] ========
__global__ __launch_bounds__(256) void k_ck(const float* __restrict__ proj,
                                            float* __restrict__ ckb,
                                            const float* __restrict__ temp,
                                            const float* __restrict__ sigma,
                                            int H, int W) {
    __shared__ __align__(16) float smem[9680];   // halo [484][20]

    int tid = threadIdx.x;
    int tx = tid & 15, ty = tid >> 4;
    int x0 = blockIdx.x * 16, y0 = blockIdx.y * 16;
    int b = blockIdx.z;

    float ck[49];
#pragma unroll
    for (int p = 0; p < 49; p++) ck[p] = 0.f;

    const float* pb = proj + (long)b * 32 * H * W;
    const f4* hs4 = (const f4*)smem;
#pragma unroll 1
    for (int pass = 0; pass < 2; pass++) {
        int k0 = pass * 16;
        for (int i = tid; i < 16 * 484; i += 256) {
            int k = i / 484;
            int rem = i - k * 484;
            int yy = rem / 22, xx = rem - yy * 22;
            int y = y0 - 3 + yy; y = y < 0 ? -y : (y >= H ? 2 * H - 2 - y : y);
            int x = x0 - 3 + xx; x = x < 0 ? -x : (x >= W ? 2 * W - 2 - x : x);
            smem[rem * 20 + k] = pb[((long)(k0 + k) * H + y) * W + x];
        }
        __syncthreads();
        int pc = ((ty + 3) * 22 + (tx + 3)) * 5;
        f4 c0 = hs4[pc + 0], c1 = hs4[pc + 1], c2 = hs4[pc + 2], c3 = hs4[pc + 3];
#pragma unroll
        for (int dy = 0; dy < 7; dy++) {
#pragma unroll
            for (int dx = 0; dx < 7; dx++) {
                int pn = ((ty + dy) * 22 + (tx + dx)) * 5;
                f4 s = hs4[pn + 0] * c0;
                s += hs4[pn + 1] * c1;
                s += hs4[pn + 2] * c2;
                s += hs4[pn + 3] * c3;
                ck[dy * 7 + dx] += (s.x + s.y) + (s.z + s.w);
            }
        }
        __syncthreads();
    }

    // softmax * spatial, renormalize (registers only)
    {
        float t = expf(temp[0]);
        t = fminf(fmaxf(t, 1e-4f), 1e4f);
        float m = -1e30f;
#pragma unroll
        for (int p = 0; p < 49; p++) { ck[p] *= t; m = fmaxf(m, ck[p]); }
        float ssum = 0.f;
#pragma unroll
        for (int p = 0; p < 49; p++) { ck[p] = expf(ck[p] - m); ssum += ck[p]; }
        float inv = 1.f / ssum;
        float sg = sigma[0];
        float dc = 1.f / (2.f * sg * sg);
        float csum = 0.f;
#pragma unroll
        for (int p = 0; p < 49; p++) {
            int dy = p / 7, dx = p % 7;
            float d0 = (dy - 3) / 3.f, d1 = (dx - 3) / 3.f;
            float sp = expf(-(d0 * d0 + d1 * d1) * dc);
            ck[p] = ck[p] * inv * sp;
            csum += ck[p];
        }
        float r = 1.f / fmaxf(csum, 1e-7f);
#pragma unroll
        for (int p = 0; p < 49; p++) ck[p] *= r;
    }

    // write out: [b][p][y][x], coalesced over tx
    long HWl = (long)H * W;
    float* cp = ckb + (long)b * 49 * HWl + (long)(y0 + ty) * W + (x0 + tx);
#pragma unroll
    for (int p = 0; p < 49; p++) cp[(long)p * HWl] = ck[p];
}

// ======== k_apply: bicubic-in-LDS + 49-tap apply, 2 px/thread (ck STREAMED) ========
// Block = 16 rows x 32 px cols (each thread owns 2 horizontally-adjacent pixels);
// adjacent pixels share 6/7 tap columns -> 8-column union serves both: apply LDS
// reads drop to 0.65x per pixel (the kernel was LDS-issue bound: ~160us of 214 was
// b128 issue). LDS 59.7 KB -> 2 blocks/CU (fine: throughput-bound, not latency).
// ck streamed 7+7 per dy per chunk. PLAIN __launch_bounds__(256) — min-waves caps
// collapse the allocator to 64-84 VGPR + wholesale scratch spill (4 trials).
// Layout [row][g][39] keeps the same 4-way-quad bank pattern as the 1-px version.
template <int CS>
__global__ __launch_bounds__(256) void k_apply(const float* __restrict__ lo,
                                               const float* ckb,
                                               float* out,
                                               int H, int W, int h, int w) {
    __shared__ __align__(16) float smem[14928];   // lo4 768 f4 | tmp4 1248 f4 | hr4 1716 f4

    int tid = threadIdx.x;
    int tx = tid & 15, ty = tid >> 4;
    int x0 = blockIdx.x * 32, y0 = blockIdx.y * 16;
    int b = blockIdx.z / CS;
    int c_base = (blockIdx.z % CS) * (256 / CS);

    int HW = H * W;
    int xp = x0 + 2 * tx;                    // left pixel of this thread's pair
    const float* cp = ckb + (long)b * 49 * HW + (y0 + ty) * W + xp;

    // ---- contiguous 22(y) x 38(x) window covering all reflect-padded taps ----
    int ws_y = y0 - 3; if (ws_y < 0) ws_y = 0; if (ws_y > H - 22) ws_y = H - 22;
    int ws_x = x0 - 3; if (ws_x < 0) ws_x = 0; if (ws_x > W - 38) ws_x = W - 38;
    int ls_y = (ws_y >> 1) - 2, ls_x = (ws_x >> 1) - 2;
    int ry[7];    // row offsets pre-scaled by 78 (f4 row stride)
#pragma unroll
    for (int d = 0; d < 7; d++) {
        int v = y0 + ty + d - 3; v = v < 0 ? -v : (v >= H ? 2 * H - 2 - v : v);
        ry[d] = (v - ws_y) * 78;
    }
    int rxu[8];   // union tap columns for the pixel pair (px0: 0..6, px1: 1..7)
#pragma unroll
    for (int d = 0; d < 8; d++) {
        int u = xp + d - 3; u = u < 0 ? -u : (u >= W ? 2 * W - 2 - u : u);
        rxu[d] = u - ws_x;
    }

    // f4 tiles: [row][g][col] — lo4 [16][2][24], tmp4 [16][2][39], hr4 [22][2][39]
    f4* lo4  = (f4*)smem;            // 768 f4
    f4* tmp4 = ((f4*)smem) + 768;    // 1248 f4
    f4* hr4  = ((f4*)smem) + 2016;   // 1716 f4

    int hw = h * w;

    const int nchunk = (256 / CS) / 8;
#pragma unroll 1
    for (int cc = 0; cc < nchunk; cc++) {
        int c0 = c_base + cc * 8;
        // stage lo: 16 rows x 23 cols, 8 channels as two f4 groups
        const float* lpb = lo + (long)(b * 256 + c0) * hw;
#pragma unroll
        for (int it = 0; it < 2; it++) {
            int e = tid + it * 256;
            if (e < 368) {
                int r = e / 23, c = e - r * 23;
                int lr = ls_y + r; lr = lr < 0 ? 0 : (lr >= h ? h - 1 : lr);
                int lc = ls_x + c; lc = lc < 0 ? 0 : (lc >= w ? w - 1 : lc);
                const float* lp = lpb + lr * w + lc;
                f4 va;
                va.x = lp[0];      va.y = lp[hw];     va.z = lp[2 * hw]; va.w = lp[3 * hw];
                lo4[r * 48 + c] = va;
                f4 vb;
                vb.x = lp[4 * hw]; vb.y = lp[5 * hw]; vb.z = lp[6 * hw]; vb.w = lp[7 * hw];
                lo4[r * 48 + 24 + c] = vb;
            }
        }
        __syncthreads();

        // horizontal bicubic: tmp [16 lo-rows][38 hr-cols][2 g] (1216 f4)
#pragma unroll
        for (int it = 0; it < 5; it++) {
            int e = tid + it * 256;
            if (e < 1216) {
                int g = e & 1, rem = e >> 1;
                int j = rem / 38, Xp = rem - j * 38;
                int X = ws_x + Xp;
                int ix = (X >> 1) - ls_x;
                const f4* lr = lo4 + j * 48 + g * 24;
                f4 v;
                if (X & 1)
                    v = -0.10546875f * lr[ix - 1] + 0.87890625f * lr[ix] + 0.26171875f * lr[ix + 1] - 0.03515625f * lr[ix + 2];
                else
                    v = -0.03515625f * lr[ix - 2] + 0.26171875f * lr[ix - 1] + 0.87890625f * lr[ix] - 0.10546875f * lr[ix + 1];
                tmp4[j * 78 + g * 39 + Xp] = v;
            }
        }
        __syncthreads();

        // vertical bicubic: hr [22 rows][38 cols][2 g] (1672 f4)
#pragma unroll
        for (int it = 0; it < 7; it++) {
            int e = tid + it * 256;
            if (e < 1672) {
                int g = e & 1, rem = e >> 1;
                int i = rem / 38, Xp = rem - i * 38;
                int Y = ws_y + i;
                int jy = (Y >> 1) - ls_y;
                const f4* tc = tmp4 + g * 39 + Xp;
                f4 v;
                if (Y & 1)
                    v = -0.10546875f * tc[(jy - 1) * 78] + 0.87890625f * tc[jy * 78] + 0.26171875f * tc[(jy + 1) * 78] - 0.03515625f * tc[(jy + 2) * 78];
                else
                    v = -0.03515625f * tc[(jy - 2) * 78] + 0.26171875f * tc[(jy - 1) * 78] + 0.87890625f * tc[jy * 78] - 0.10546875f * tc[(jy + 1) * 78];
                hr4[i * 78 + g * 39 + Xp] = v;
            }
        }
        __syncthreads();

        // apply 49 taps for BOTH pixels; 8-column tap union shared across the pair
        f4 a00 = (f4)(0.f), a01 = (f4)(0.f);   // px0: g0, g1
        f4 a10 = (f4)(0.f), a11 = (f4)(0.f);   // px1: g0, g1
#pragma unroll
        for (int dy = 0; dy < 7; dy++) {
            float c0_[7], c1_[7];
            int cko = dy * 7 * HW;
#pragma unroll
            for (int dx = 0; dx < 7; dx++) {
                c0_[dx] = cp[cko + dx * HW];
                c1_[dx] = cp[cko + dx * HW + 1];
            }
            const f4* hrow = hr4 + ry[dy];
            f4 h0[8], h1[8];
#pragma unroll
            for (int d = 0; d < 8; d++) {
                h0[d] = hrow[rxu[d]];
                h1[d] = hrow[39 + rxu[d]];
            }
#pragma unroll
            for (int dx = 0; dx < 7; dx++) {
                a00 += c0_[dx] * h0[dx];
                a01 += c0_[dx] * h1[dx];
                a10 += c1_[dx] * h0[dx + 1];
                a11 += c1_[dx] * h1[dx + 1];
            }
        }
        float* op = out + ((long)(b * 256 + c0) * H + (y0 + ty)) * W + xp;
        op[0]          = a00.x;
        op[HW]         = a00.y;
        op[2 * HW]     = a00.z;
        op[3 * HW]     = a00.w;
        op[4 * HW]     = a01.x;
        op[5 * HW]     = a01.y;
        op[6 * HW]     = a01.z;
        op[7 * HW]     = a01.w;
        op[1]          = a10.x;
        op[HW + 1]     = a10.y;
        op[2 * HW + 1] = a10.z;
        op[3 * HW + 1] = a10.w;
        op[4 * HW + 1] = a11.x;
        op[5 * HW + 1] = a11.y;
        op[6 * HW + 1] = a11.z;
        op[7 * HW + 1] = a11.w;
        // no trailing barrier: next chunk's stage-sync orders apply reads vs later writes
    }
}

// ---------------- prep: pack W[o][c] fp32 -> bf16 MFMA A-fragment order ----------------
__global__ void k_prepw(const float* __restrict__ w, unsigned short* __restrict__ wf) {
    int blk = blockIdx.x;           // mt*16+ks, 128 blocks
    int lane = threadIdx.x;         // 64
    int mt = blk >> 4, ks = blk & 15;
    int o = mt * 32 + (lane & 31);
    int c = ks * 16 + (lane >> 5) * 8;
    const float* wp = w + (long)o * 256 + c;
    float4 v0 = *(const float4*)wp;
    float4 v1 = *(const float4*)(wp + 4);
    unsigned short* dst = wf + ((long)(blk * 64 + lane)) * 8;
    unsigned int r0 = f2bf(v0.x) | ((unsigned int)f2bf(v0.y) << 16);
    unsigned int r1 = f2bf(v0.z) | ((unsigned int)f2bf(v0.w) << 16);
    unsigned int r2 = f2bf(v1.x) | ((unsigned int)f2bf(v1.y) << 16);
    unsigned int r3 = f2bf(v1.z) | ((unsigned int)f2bf(v1.w) << 16);
    uint4 pk = {r0, r1, r2, r3};
    *(uint4*)dst = pk;
}

// ---------------- MFMA GEMM: y = W @ x (+ GN-fold / + residual + GN-stat partials) ----
#define LDK 264
template <bool GN, bool RESID>
__global__ __launch_bounds__(256) void k_gemm256(float* __restrict__ x,
                                                 const unsigned short* __restrict__ wf,
                                                 const float* __restrict__ stats,
                                                 const float* __restrict__ gn_w,
                                                 const float* __restrict__ gn_b,
                                                 float* __restrict__ part) {
    __shared__ unsigned short xs[64 * LDK];
    __shared__ float scl_s[256], sh_s[256];
    __shared__ float gs[64];
    int tid = threadIdx.x;
    int b = blockIdx.y;
    int pix0 = blockIdx.x * 64;
    float* xb = x + (long)b * 256 * HW2;

    if (RESID && tid < 64) gs[tid] = 0.f;

    if (GN) {
        int c = tid;
        int g = c >> 3;
        float mean = stats[(b * 32 + g) * 2];
        float rstd = stats[(b * 32 + g) * 2 + 1];
        float s = rstd * gn_w[c];
        scl_s[c] = s;
        sh_s[c] = gn_b[c] - mean * s;
        __syncthreads();
    }

#pragma unroll
    for (int it = 0; it < 4; it++) {
        int c0 = ((tid >> 4) << 2) + it * 64;
        int px = (tid & 15) << 2;
        const float* gp = xb + (long)c0 * HW2 + pix0 + px;
        float4 v0 = *(const float4*)gp;
        float4 v1 = *(const float4*)(gp + HW2);
        float4 v2 = *(const float4*)(gp + 2 * HW2);
        float4 v3 = *(const float4*)(gp + 3 * HW2);
        if (GN) {
            float s0 = scl_s[c0], h0 = sh_s[c0];
            float s1 = scl_s[c0 + 1], h1 = sh_s[c0 + 1];
            float s2 = scl_s[c0 + 2], h2 = sh_s[c0 + 2];
            float s3 = scl_s[c0 + 3], h3 = sh_s[c0 + 3];
            v0.x = v0.x * s0 + h0; v0.y = v0.y * s0 + h0; v0.z = v0.z * s0 + h0; v0.w = v0.w * s0 + h0;
            v1.x = v1.x * s1 + h1; v1.y = v1.y * s1 + h1; v1.z = v1.z * s1 + h1; v1.w = v1.w * s1 + h1;
            v2.x = v2.x * s2 + h2; v2.y = v2.y * s2 + h2; v2.z = v2.z * s2 + h2; v2.w = v2.w * s2 + h2;
            v3.x = v3.x * s3 + h3; v3.y = v3.y * s3 + h3; v3.z = v3.z * s3 + h3; v3.w = v3.w * s3 + h3;
        }
        float p0[4] = {v0.x, v0.y, v0.z, v0.w};
        float p1[4] = {v1.x, v1.y, v1.z, v1.w};
        float p2[4] = {v2.x, v2.y, v2.z, v2.w};
        float p3[4] = {v3.x, v3.y, v3.z, v3.w};
#pragma unroll
        for (int p = 0; p < 4; p++) {
            ushort4 u;
            u.x = f2bf(p0[p]); u.y = f2bf(p1[p]); u.z = f2bf(p2[p]); u.w = f2bf(p3[p]);
            *(ushort4*)&xs[(px + p) * LDK + c0] = u;
        }
    }
    __syncthreads();

    int lane = tid & 63, wv = tid >> 6;
    fvec16 acc[2][2];
#pragma unroll
    for (int mi = 0; mi < 2; mi++)
#pragma unroll
        for (int ni = 0; ni < 2; ni++)
            acc[mi][ni] = (fvec16)(0.f);

    int n_in = lane & 31;
    int koff = (lane >> 5) * 8;
#pragma unroll
    for (int ks = 0; ks < 16; ks++) {
        s8b a0 = *(const s8b*)(wf + ((long)(((wv * 2 + 0) * 16 + ks) * 64 + lane)) * 8);
        s8b a1 = *(const s8b*)(wf + ((long)(((wv * 2 + 1) * 16 + ks) * 64 + lane)) * 8);
        s8b b0 = *(const s8b*)&xs[(0 + n_in) * LDK + ks * 16 + koff];
        s8b b1 = *(const s8b*)&xs[(32 + n_in) * LDK + ks * 16 + koff];
        acc[0][0] = __builtin_amdgcn_mfma_f32_32x32x16_bf16(a0, b0, acc[0][0], 0, 0, 0);
        acc[0][1] = __builtin_amdgcn_mfma_f32_32x32x16_bf16(a0, b1, acc[0][1], 0, 0, 0);
        acc[1][0] = __builtin_amdgcn_mfma_f32_32x32x16_bf16(a1, b0, acc[1][0], 0, 0, 0);
        acc[1][1] = __builtin_amdgcn_mfma_f32_32x32x16_bf16(a1, b1, acc[1][1], 0, 0, 0);
    }

    int hh = lane >> 5;
    float ls[2][4], lq[2][4];
    if (RESID) {
#pragma unroll
        for (int mi = 0; mi < 2; mi++)
#pragma unroll
            for (int gq = 0; gq < 4; gq++) { ls[mi][gq] = 0.f; lq[mi][gq] = 0.f; }
    }
#pragma unroll
    for (int mi = 0; mi < 2; mi++) {
        int mt = wv * 2 + mi;
#pragma unroll
        for (int ni = 0; ni < 2; ni++) {
            int pix = pix0 + ni * 32 + n_in;
#pragma unroll
            for (int r = 0; r < 16; r++) {
                int row = (r & 3) + 8 * (r >> 2) + 4 * hh;
                long addr = (long)(mt * 32 + row) * HW2 + pix;
                if (RESID) {
                    float v = xb[addr] + 0.1f * acc[mi][ni][r];
                    xb[addr] = v;
                    ls[mi][r >> 2] += v;
                    lq[mi][r >> 2] += v * v;
                } else {
                    xb[addr] = acc[mi][ni][r];
                }
            }
        }
    }
    if (RESID) {
#pragma unroll
        for (int mi = 0; mi < 2; mi++)
#pragma unroll
            for (int gq = 0; gq < 4; gq++) {
                int g = (wv * 2 + mi) * 4 + gq;
                atomicAdd(&gs[g * 2], ls[mi][gq]);
                atomicAdd(&gs[g * 2 + 1], lq[mi][gq]);
            }
        __syncthreads();
        if (tid < 64) {
            int g = tid >> 1, which = tid & 1;
            part[((long)(b * 32 + g) * 960 + blockIdx.x) * 2 + which] = gs[tid];
        }
    }
}

// ---------------- GroupNorm stats reduce: 960 tile-partials -> mean/rstd ----------------
__global__ void k_gnred2(const float* __restrict__ part, float* __restrict__ stats) {
    __shared__ double s_s[256], q_s[256];
    int t = blockIdx.x;   // b*32+g
    const float* p = part + (long)t * 960 * 2;
    double s = 0.0, q = 0.0;
    for (int i = threadIdx.x; i < 960; i += 256) {
        s += p[2 * i];
        q += p[2 * i + 1];
    }
    s_s[threadIdx.x] = s; q_s[threadIdx.x] = q;
    __syncthreads();
    for (int st = 128; st > 0; st >>= 1) {
        if (threadIdx.x < st) { s_s[threadIdx.x] += s_s[threadIdx.x + st]; q_s[threadIdx.x] += q_s[threadIdx.x + st]; }
        __syncthreads();
    }
    if (threadIdx.x == 0) {
        double N = 8.0 * HW2;
        double mean = s_s[0] / N;
        double var = q_s[0] / N - mean * mean;
        stats[t * 2] = (float)mean;
        stats[t * 2 + 1] = (float)(1.0 / sqrt(var + 1e-5));
    }
}

extern "C" void kernel_launch(void* const* d_in, const int* in_sizes, int n_in,
                              void* d_out, int out_size, void* d_ws, size_t ws_size,
                              hipStream_t stream) {
    const float* src      = (const float*)d_in[0];
    const float* guidance = (const float*)d_in[1];
    const float* pre_w    = (const float*)d_in[2];
    const float* rp1_w1   = (const float*)d_in[3];
    const float* rp1_b1   = (const float*)d_in[4];
    const float* rp1_w2   = (const float*)d_in[5];
    const float* rp1_b2   = (const float*)d_in[6];
    const float* temp1    = (const float*)d_in[7];
    const float* sigma1   = (const float*)d_in[8];
    const float* rp2_w1   = (const float*)d_in[9];
    const float* rp2_b1   = (const float*)d_in[10];
    const float* rp2_w2   = (const float*)d_in[11];
    const float* rp2_b2   = (const float*)d_in[12];
    const float* temp2    = (const float*)d_in[13];
    const float* sigma2   = (const float*)d_in[14];
    const float* fixup_w  = (const float*)d_in[15];
    const float* gn_w     = (const float*)d_in[16];
    const float* gn_b     = (const float*)d_in[17];
    const float* proj_w   = (const float*)d_in[18];
    float* out = (float*)d_out;

    // ---- workspace arena ----
    char* ws = (char*)d_ws;
    size_t off = 0;
    auto alloc = [&](size_t bytes) { size_t o = off; off = (off + bytes + 255) & ~(size_t)255; return o; };
    float* gdown  = (float*)(ws + alloc((size_t)2 * 3 * 192 * 1280 * 4));
    float* gbuf   = (float*)(ws + alloc((size_t)2 * 3 * 192 * 320 * 4));
    float* projb  = (float*)(ws + alloc((size_t)2 * 32 * 192 * 320 * 4));
    float* x1     = (float*)(ws + alloc((size_t)2 * 256 * 48 * 80 * 4));
    float* out1   = (float*)(ws + alloc((size_t)2 * 256 * 96 * 160 * 4));
    float* ckbuf  = (float*)(ws + alloc((size_t)2 * 49 * 192 * 320 * 4));   // reused across steps
    unsigned short* wfFix  = (unsigned short*)(ws + alloc(65536 * 2));
    unsigned short* wfProj = (unsigned short*)(ws + alloc(65536 * 2));
    float* gpart  = (float*)(ws + alloc((size_t)64 * 960 * 2 * 4));
    float* stats  = (float*)(ws + alloc(64 * 2 * 4));

    // weight prep (bf16 MFMA fragment order)
    k_prepw<<<128, 64, 0, stream>>>(fixup_w, wfFix);
    k_prepw<<<128, 64, 0, stream>>>(proj_w, wfProj);

    // pre-projection 384->256 (2 outputs per block)
    k_preproj<<<256, 256, 0, stream>>>(src, pre_w, x1);

    // ---- JBU step 1: 48x80 -> 96x160 ----
    {
        const int H = 96, W = 160, HW = H * W;
        k_down_h<<<(2 * 3 * H * 1280) / 256, 256, 0, stream>>>(guidance, gdown, H, 8.f);
        k_down_w<<<(2 * 3 * HW + 255) / 256, 256, 0, stream>>>(gdown, gbuf, H, W, 8.f);
        k_proj<<<(2 * HW + 255) / 256, 256, 0, stream>>>(gbuf, projb, rp1_w1, rp1_b1, rp1_w2, rp1_b2, HW);
        k_ck<<<dim3(W / 16, H / 16, 2), 256, 0, stream>>>(projb, ckbuf, temp1, sigma1, H, W);
        k_apply<8><<<dim3(W / 32, H / 16, 2 * 8), 256, 0, stream>>>(x1, ckbuf, out1, H, W, 48, 80);
    }

    // ---- JBU step 2: 96x160 -> 192x320 ----
    {
        const int H = 192, W = 320, HW = H * W;
        k_down_h<<<(2 * 3 * H * 1280) / 256, 256, 0, stream>>>(guidance, gdown, H, 4.f);
        k_down_w<<<(2 * 3 * HW + 255) / 256, 256, 0, stream>>>(gdown, gbuf, H, W, 4.f);
        k_proj<<<(2 * HW + 255) / 256, 256, 0, stream>>>(gbuf, projb, rp2_w1, rp2_b1, rp2_w2, rp2_b2, HW);
        k_ck<<<dim3(W / 16, H / 16, 2), 256, 0, stream>>>(projb, ckbuf, temp2, sigma2, H, W);
        k_apply<8><<<dim3(W / 32, H / 16, 2 * 8), 256, 0, stream>>>(out1, ckbuf, out, H, W, 96, 160);
    }

    // ---- fixup residual (+ fused GN-stat partials): out = out + 0.1 * W @ out ----
    k_gemm256<false, true><<<dim3(960, 2), 256, 0, stream>>>(out, wfFix, nullptr, nullptr, nullptr, gpart);
    // ---- GroupNorm stats reduce (parallel) ----
    k_gnred2<<<64, 256, 0, stream>>>(gpart, stats);
    // ---- GN affine + final projection (MFMA, in-place) ----
    k_gemm256<true, false><<<dim3(960, 2), 256, 0, stream>>>(out, wfProj, stats, gn_w, gn_b, nullptr);
}